// Round 12
// baseline (1083.379 us; speedup 1.0000x reference)
//
#include <hip/hip_runtime.h>
#include <cstdint>

#define NE_N   100000
#define NPER_N 50000
#define HD     128
#define OUTD   64
#define NEE    1600000
#define NPE    800000
#define NEP    800000
#define ETOT   (NEE+NPE+NEP)

static inline int ceil_div(long long a, long long b){ return (int)((a + b - 1)/b); }

__device__ __forceinline__ float4 ld4(const float* p){ return *reinterpret_cast<const float4*>(p); }
__device__ __forceinline__ void st4(float* p, float4 v){ *reinterpret_cast<float4*>(p) = v; }
__device__ __forceinline__ uint16_t f2b(float f){            // fp32 -> bf16 RNE
    uint32_t u = __float_as_uint(f);
    u += 0x7fffu + ((u >> 16) & 1u);
    return (uint16_t)(u >> 16);
}
__device__ __forceinline__ float b2f(uint32_t u){ return __uint_as_float(u << 16); }

typedef short v8s __attribute__((ext_vector_type(8)));
typedef float v4f __attribute__((ext_vector_type(4)));
typedef unsigned int v4u __attribute__((ext_vector_type(4)));   // nt-loadable uint4
typedef float v4fl __attribute__((ext_vector_type(4)));         // nt-loadable float4

// ================= MFMA bf16 GEMM =================
// mode: 0 = f32 out + bias ; 1 = bf16 out ; 2 = bf16 + bias + relu ; 3 = bf16 + bias
struct Seg { const uint16_t* W; const float* b; void* C; int ldw; int ldc; int mode; };
struct Segs { Seg s[6]; };

template<int K>
__global__ __launch_bounds__(256)
void gemm_mfma(const uint16_t* __restrict__ A, int N, Segs segs)
{
    constexpr int NKS  = K / 32;
    constexpr int PADK = K + 8;
    __shared__ __align__(16) uint16_t Wt[64 * PADK];

    Seg sg = segs.s[blockIdx.y];

    const int t = threadIdx.x;
    for (int i = t; i < K*64; i += 256){
        int k = i >> 6, c = i & 63;
        Wt[c*PADK + k] = sg.W[(size_t)k*sg.ldw + c];
    }
    __syncthreads();

    const int lane = t & 63, wid = t >> 6;
    const int l16 = lane & 15, lg = lane >> 4;
    const int rowbase = blockIdx.x*256 + wid*64;

    v4f acc[4][4];
#pragma unroll
    for (int i=0;i<4;i++)
#pragma unroll
        for (int j=0;j<4;j++) acc[i][j] = (v4f){0.f,0.f,0.f,0.f};

#pragma unroll
    for (int ks=0; ks<NKS; ks++){
        const int koff = ks*32 + lg*8;
        v8s a[4], b[4];
#pragma unroll
        for (int rt=0;rt<4;rt++){
            int r = rowbase + rt*16 + l16; if (r > N-1) r = N-1;
            a[rt] = *reinterpret_cast<const v8s*>(&A[(size_t)r*K + koff]);
        }
#pragma unroll
        for (int ct=0;ct<4;ct++)
            b[ct] = *reinterpret_cast<const v8s*>(&Wt[(ct*16 + l16)*PADK + koff]);
#pragma unroll
        for (int rt=0;rt<4;rt++)
#pragma unroll
            for (int ct=0;ct<4;ct++)
                acc[rt][ct] = __builtin_amdgcn_mfma_f32_16x16x32_bf16(a[rt], b[ct], acc[rt][ct], 0, 0, 0);
    }

    const int mode = sg.mode, ldc = sg.ldc;
    float bias[4];
    if (mode != 1){
#pragma unroll
        for (int ct=0;ct<4;ct++) bias[ct] = sg.b[ct*16 + l16];
    }
#pragma unroll
    for (int rt=0;rt<4;rt++){
#pragma unroll
        for (int rg=0;rg<4;rg++){
            int r = rowbase + rt*16 + lg*4 + rg;
            if (r < N){
#pragma unroll
                for (int ct=0;ct<4;ct++){
                    float v = acc[rt][ct][rg];
                    int c = ct*16 + l16;
                    if (mode == 0)
                        ((float*)sg.C)[(size_t)r*ldc + c] = v + bias[ct];
                    else if (mode == 1)
                        ((uint16_t*)sg.C)[(size_t)r*ldc + c] = f2b(v);
                    else if (mode == 2)
                        ((uint16_t*)sg.C)[(size_t)r*ldc + c] = f2b(fmaxf(v + bias[ct], 0.f));
                    else
                        ((uint16_t*)sg.C)[(size_t)r*ldc + c] = f2b(v + bias[ct]);
                }
            }
        }
    }
}

// ================= CSR build =================
__global__ void count_all(const int* __restrict__ ee, const int* __restrict__ pe,
                          const int* __restrict__ ep, int* __restrict__ cnt){
    int i = blockIdx.x*blockDim.x + threadIdx.x;
    if (i < NEE) atomicAdd(&cnt[__builtin_nontemporal_load(&ee[i])], 1);
    else if (i < NEE+NPE) atomicAdd(&cnt[100000 + __builtin_nontemporal_load(&pe[i-NEE])], 1);
    else if (i < ETOT) atomicAdd(&cnt[200000 + __builtin_nontemporal_load(&ep[i-NEE-NPE])], 1);
}
__global__ __launch_bounds__(256)
void scan_block3(const int* __restrict__ cnt_all, int* __restrict__ ee_off,
                 int* __restrict__ pe_off, int* __restrict__ ep_off,
                 int* __restrict__ partial){
    int r = blockIdx.y;
    const int* cnt = cnt_all + (r==0 ? 0 : (r==1 ? 100000 : 200000));
    int* off = (r==0) ? ee_off : (r==1 ? pe_off : ep_off);
    int n = (r==2) ? NPER_N : NE_N;
    int* part = partial + r*128;

    __shared__ int sh[256];
    int t = threadIdx.x;
    int base = blockIdx.x*1024 + t*4;
    int v0 = (base  <n)?cnt[base  ]:0;
    int v1 = (base+1<n)?cnt[base+1]:0;
    int v2 = (base+2<n)?cnt[base+2]:0;
    int v3 = (base+3<n)?cnt[base+3]:0;
    int tsum = v0+v1+v2+v3;
    sh[t]=tsum; __syncthreads();
    for (int d=1; d<256; d<<=1){
        int x = (t>=d)? sh[t-d] : 0;
        __syncthreads();
        sh[t] += x;
        __syncthreads();
    }
    int ex = sh[t]-tsum;
    if (base  <n) off[base  ]=ex;
    if (base+1<n) off[base+1]=ex+v0;
    if (base+2<n) off[base+2]=ex+v0+v1;
    if (base+3<n) off[base+3]=ex+v0+v1+v2;
    if (t==255) part[blockIdx.x]=sh[255];
}
__global__ void scan_partial3(int* __restrict__ partial){
    int r = blockIdx.x;
    if (threadIdx.x != 0) return;
    int n = (r==2) ? NPER_N : NE_N;
    int nb = (n + 1023) >> 10;
    int* p = partial + r*128;
    int run = 0;
    for (int i=0;i<nb;i++){ int v=p[i]; p[i]=run; run+=v; }
}
__global__ void add_base3(int* __restrict__ ee_off, int* __restrict__ pe_off,
                          int* __restrict__ ep_off, const int* __restrict__ partial){
    int i = blockIdx.x*blockDim.x + threadIdx.x;
    if (i <= NE_N){
        if (i < NE_N) ee_off[i] += partial[i>>10];
        else ee_off[NE_N] = NEE;
    } else if (i <= 2*NE_N + 1){
        int k = i - (NE_N+1);
        if (k < NE_N) pe_off[k] += partial[128 + (k>>10)];
        else pe_off[NE_N] = NPE;
    } else {
        int k = i - 2*(NE_N+1);
        if (k < NPER_N) ep_off[k] += partial[256 + (k>>10)];
        else if (k == NPER_N) ep_off[NPER_N] = NEP;
    }
}
// XCD-sharded fill (dst-range r = blockIdx&7); nt loads keep edge streams out of L2
__global__ void fill_sharded(const int* __restrict__ ee_src, const int* __restrict__ ee_dst,
                             const int* __restrict__ pe_src, const int* __restrict__ pe_dst,
                             const int* __restrict__ ep_src, const int* __restrict__ ep_dst,
                             const int* __restrict__ ee_off, const int* __restrict__ pe_off,
                             const int* __restrict__ ep_off, int* __restrict__ cnt_all,
                             int* __restrict__ ee_csr, int* __restrict__ pe_csr,
                             int* __restrict__ ep_csr){
    int r = blockIdx.x & 7;
    int i = (blockIdx.x >> 3)*256 + threadIdx.x;
    int d, base, n;
    const int* srcp; const int* offp; int* csrp;
    if (i < NEE){ d = __builtin_nontemporal_load(&ee_dst[i]); base = 0; n = NE_N; srcp = ee_src; offp = ee_off; csrp = ee_csr; }
    else if (i < NEE+NPE){ i -= NEE; d = __builtin_nontemporal_load(&pe_dst[i]); base = 100000; n = NE_N; srcp = pe_src; offp = pe_off; csrp = pe_csr; }
    else if (i < ETOT){ i -= NEE+NPE; d = __builtin_nontemporal_load(&ep_dst[i]); base = 200000; n = NPER_N; srcp = ep_src; offp = ep_off; csrp = ep_csr; }
    else return;
    int seg = n >> 3;
    if (d >= r*seg && d < (r+1)*seg){
        int old = atomicAdd(&cnt_all[base + d], -1);
        csrp[offp[d] + old - 1] = __builtin_nontemporal_load(&srcp[i]);
    }
}

// ================= gather helpers (full/tail split, nt csr loads) =================
__device__ __forceinline__ void gadd128(float* acc, const uint16_t* __restrict__ proj,
                                        int sg, int l16){
    uint4 u = *reinterpret_cast<const uint4*>(&proj[(size_t)sg*128 + l16*8]);
    acc[0]+=b2f(u.x&0xffffu); acc[1]+=b2f(u.x>>16);
    acc[2]+=b2f(u.y&0xffffu); acc[3]+=b2f(u.y>>16);
    acc[4]+=b2f(u.z&0xffffu); acc[5]+=b2f(u.z>>16);
    acc[6]+=b2f(u.w&0xffffu); acc[7]+=b2f(u.w>>16);
}
__device__ __forceinline__ void gather128(const uint16_t* __restrict__ proj,
                                          const int* __restrict__ csr,
                                          int b, int e, int lane, int grp, int l16,
                                          float* acc){
    int nfull = (e - b) >> 6;
    for (int cc=0; cc<nfull; cc++){
        int s = __builtin_nontemporal_load(&csr[b + cc*64 + lane]);
#pragma unroll
        for (int k=0;k<16;k++) gadd128(acc, proj, __shfl(s, k*4 + grp, 64), l16);
    }
    int cb = b + nfull*64;
    if (cb < e){
        int j = cb + lane;
        int s = (j<e) ? __builtin_nontemporal_load(&csr[j]) : -1;
        int iters = (e - cb + 3) >> 2;
        for (int k=0;k<iters;k++){
            int sg = __shfl(s, k*4 + grp, 64);
            if (sg >= 0) gadd128(acc, proj, sg, l16);
        }
    }
}
__device__ __forceinline__ void gadd64(float* acc, const uint16_t* __restrict__ proj,
                                       int sg, int l16){
    uint2 u = *reinterpret_cast<const uint2*>(&proj[(size_t)sg*64 + l16*4]);
    acc[0]+=b2f(u.x&0xffffu); acc[1]+=b2f(u.x>>16);
    acc[2]+=b2f(u.y&0xffffu); acc[3]+=b2f(u.y>>16);
}
__device__ __forceinline__ void gather64(const uint16_t* __restrict__ proj,
                                         const int* __restrict__ csr,
                                         int b, int e, int lane, int grp, int l16,
                                         float* acc){
    int nfull = (e - b) >> 6;
    for (int cc=0; cc<nfull; cc++){
        int s = __builtin_nontemporal_load(&csr[b + cc*64 + lane]);
#pragma unroll
        for (int k=0;k<16;k++) gadd64(acc, proj, __shfl(s, k*4 + grp, 64), l16);
    }
    int cb = b + nfull*64;
    if (cb < e){
        int j = cb + lane;
        int s = (j<e) ? __builtin_nontemporal_load(&csr[j]) : -1;
        int iters = (e - cb + 3) >> 2;
        for (int k=0;k<iters;k++){
            int sg = __shfl(s, k*4 + grp, 64);
            if (sg >= 0) gadd64(acc, proj, sg, l16);
        }
    }
}

// fused conv1 aggregation: waves [0,NE_N) -> emp1, [NE_N, NE_N+NPER_N) -> per1
__global__ __launch_bounds__(256)
void agg1_fused(const uint16_t* __restrict__ proj_ee, const uint16_t* __restrict__ proj_pe,
                const uint16_t* __restrict__ proj_ep,
                const int* __restrict__ ee_off, const int* __restrict__ ee_csr,
                const int* __restrict__ pe_off, const int* __restrict__ pe_csr,
                const int* __restrict__ ep_off, const int* __restrict__ ep_csr,
                uint16_t* __restrict__ emp1b, uint16_t* __restrict__ per1b){
    int gw   = (blockIdx.x*blockDim.x + threadIdx.x) >> 6;
    int lane = threadIdx.x & 63;
    int grp = lane >> 4, l16 = lane & 15;

    if (gw < NE_N){
        int w = gw;
        float a[8] = {0,0,0,0,0,0,0,0};
        float c[8] = {0,0,0,0,0,0,0,0};
        int b0 = ee_off[w], e0 = ee_off[w+1];
        int b1 = pe_off[w], e1 = pe_off[w+1];
        gather128(proj_ee, ee_csr, b0, e0, lane, grp, l16, a);
        gather128(proj_pe, pe_csr, b1, e1, lane, grp, l16, c);
#pragma unroll
        for (int f=0;f<8;f++){
            a[f] += __shfl_xor(a[f],16,64); a[f] += __shfl_xor(a[f],32,64);
            c[f] += __shfl_xor(c[f],16,64); c[f] += __shfl_xor(c[f],32,64);
        }
        if (grp == 0){
            float s1f = 1.f/fmaxf((float)(e0-b0),1.f);
            float s2f = 1.f/fmaxf((float)(e1-b1),1.f);
            v4u sb = __builtin_nontemporal_load(
                reinterpret_cast<const v4u*>(&emp1b[(size_t)w*128 + l16*8]));
            float sf[8] = { b2f(sb.x&0xffffu), b2f(sb.x>>16), b2f(sb.y&0xffffu), b2f(sb.y>>16),
                            b2f(sb.z&0xffffu), b2f(sb.z>>16), b2f(sb.w&0xffffu), b2f(sb.w>>16) };
            uint4 pk;
            uint32_t o[8];
#pragma unroll
            for (int f=0;f<8;f++) o[f] = (uint32_t)f2b(fmaxf(sf[f] + a[f]*s1f + c[f]*s2f, 0.f));
            pk.x = o[0] | (o[1]<<16); pk.y = o[2] | (o[3]<<16);
            pk.z = o[4] | (o[5]<<16); pk.w = o[6] | (o[7]<<16);
            *reinterpret_cast<uint4*>(&emp1b[(size_t)w*128 + l16*8]) = pk;
        }
    } else if (gw < NE_N + NPER_N){
        int w = gw - NE_N;
        float a[8] = {0,0,0,0,0,0,0,0};
        int b0 = ep_off[w], e0 = ep_off[w+1];
        gather128(proj_ep, ep_csr, b0, e0, lane, grp, l16, a);
#pragma unroll
        for (int f=0;f<8;f++){
            a[f] += __shfl_xor(a[f],16,64); a[f] += __shfl_xor(a[f],32,64);
        }
        if (grp == 0){
            float s1f = 1.f/fmaxf((float)(e0-b0),1.f);
            v4u sb = __builtin_nontemporal_load(
                reinterpret_cast<const v4u*>(&per1b[(size_t)w*128 + l16*8]));
            float sf[8] = { b2f(sb.x&0xffffu), b2f(sb.x>>16), b2f(sb.y&0xffffu), b2f(sb.y>>16),
                            b2f(sb.z&0xffffu), b2f(sb.z>>16), b2f(sb.w&0xffffu), b2f(sb.w>>16) };
            uint4 pk;
            uint32_t o[8];
#pragma unroll
            for (int f=0;f<8;f++) o[f] = (uint32_t)f2b(fmaxf(sf[f] + a[f]*s1f, 0.f));
            pk.x = o[0] | (o[1]<<16); pk.y = o[2] | (o[3]<<16);
            pk.z = o[4] | (o[5]<<16); pk.w = o[6] | (o[7]<<16);
            *reinterpret_cast<uint4*>(&per1b[(size_t)w*128 + l16*8]) = pk;
        }
    }
}

// fused conv2 aggregation: waves [0,NE_N) -> GAT+SAGE emp2, rest -> per2
__global__ __launch_bounds__(256)
void agg2_fused(const int* __restrict__ ee_off, const int* __restrict__ ee_csr,
                const int* __restrict__ pe_off, const int* __restrict__ pe_csr,
                const int* __restrict__ ep_off, const int* __restrict__ ep_csr,
                const float* __restrict__ as, const float* __restrict__ ad,
                const uint16_t* __restrict__ zs, const uint16_t* __restrict__ p2pe,
                const uint16_t* __restrict__ p2ep,
                float* __restrict__ out_emp, float* __restrict__ out_per){
    int gw   = (blockIdx.x*blockDim.x + threadIdx.x) >> 6;
    int lane = threadIdx.x & 63;
    int grp = lane >> 4, l16 = lane & 15;

    if (gw < NE_N){
        int w = gw;
        float g[4] = {0,0,0,0};
        float invden = 0.f;
        int b = ee_off[w], e = ee_off[w+1];
        if (e > b){
            float add = ad[w];
            float m = -INFINITY;
            for (int j=b+lane; j<e; j+=64){
                float ev = as[ee_csr[j]] + add;
                ev = ev > 0.f ? ev : 0.2f*ev;
                m = fmaxf(m, ev);
            }
            for (int o=32;o;o>>=1) m = fmaxf(m, __shfl_xor(m,o,64));

            float den = 0.f;
            int nfull = (e - b) >> 6;
            for (int cc=0; cc<nfull; cc++){
                int s = ee_csr[b + cc*64 + lane];
                float ev = as[s] + add;
                ev = ev > 0.f ? ev : 0.2f*ev;
                float ex = expf(ev - m);
                den += ex;
#pragma unroll
                for (int k=0;k<16;k++){
                    int   sg = __shfl(s,  k*4 + grp, 64);
                    float ag = __shfl(ex, k*4 + grp, 64);
                    uint2 u = *reinterpret_cast<const uint2*>(&zs[(size_t)sg*64 + l16*4]);
                    g[0] += ag*b2f(u.x&0xffffu); g[1] += ag*b2f(u.x>>16);
                    g[2] += ag*b2f(u.y&0xffffu); g[3] += ag*b2f(u.y>>16);
                }
            }
            int cb = b + nfull*64;
            if (cb < e){
                int j = cb + lane;
                int s = 0; float ex = 0.f;
                if (j < e){
                    s = ee_csr[j];
                    float ev = as[s] + add;
                    ev = ev > 0.f ? ev : 0.2f*ev;
                    ex = expf(ev - m);
                }
                den += ex;
                int iters = (e - cb + 3) >> 2;
                for (int k=0;k<iters;k++){
                    int   sg = __shfl(s,  k*4 + grp, 64);
                    float ag = __shfl(ex, k*4 + grp, 64);
                    uint2 u = *reinterpret_cast<const uint2*>(&zs[(size_t)sg*64 + l16*4]);
                    g[0] += ag*b2f(u.x&0xffffu); g[1] += ag*b2f(u.x>>16);
                    g[2] += ag*b2f(u.y&0xffffu); g[3] += ag*b2f(u.y>>16);
                }
            }
            for (int o=32;o;o>>=1) den += __shfl_xor(den,o,64);
            invden = 1.f/den;
        }

        float p[4] = {0,0,0,0};
        b = pe_off[w]; e = pe_off[w+1];
        gather64(p2pe, pe_csr, b, e, lane, grp, l16, p);
#pragma unroll
        for (int f=0;f<4;f++){
            g[f] += __shfl_xor(g[f],16,64); g[f] += __shfl_xor(g[f],32,64);
            p[f] += __shfl_xor(p[f],16,64); p[f] += __shfl_xor(p[f],32,64);
        }
        if (grp == 0){
            float s2f = 1.f/fmaxf((float)(e-b),1.f);
            float4 o4 = ld4(&out_emp[(size_t)w*64 + l16*4]);
            o4.x += g[0]*invden + p[0]*s2f;
            o4.y += g[1]*invden + p[1]*s2f;
            o4.z += g[2]*invden + p[2]*s2f;
            o4.w += g[3]*invden + p[3]*s2f;
            st4(&out_emp[(size_t)w*64 + l16*4], o4);
        }
    } else if (gw < NE_N + NPER_N){
        int w = gw - NE_N;
        float a[4] = {0,0,0,0};
        int b = ep_off[w], e = ep_off[w+1];
        gather64(p2ep, ep_csr, b, e, lane, grp, l16, a);
#pragma unroll
        for (int f=0;f<4;f++){
            a[f] += __shfl_xor(a[f],16,64); a[f] += __shfl_xor(a[f],32,64);
        }
        if (grp == 0){
            float s1f = 1.f/fmaxf((float)(e-b),1.f);
            float4 o4 = ld4(&out_per[(size_t)w*64 + l16*4]);
            o4.x += a[0]*s1f; o4.y += a[1]*s1f; o4.z += a[2]*s1f; o4.w += a[3]*s1f;
            st4(&out_per[(size_t)w*64 + l16*4], o4);
        }
    }
}

__global__ void rowdots(const uint16_t* __restrict__ ZS, const uint16_t* __restrict__ E1,
                        const float* __restrict__ wa, const float* __restrict__ wv,
                        float* __restrict__ a_s, float* __restrict__ a_d){
    int wid  = (blockIdx.x*blockDim.x + threadIdx.x) >> 6;
    int lane = threadIdx.x & 63;
    if (wid < NE_N){
        float v = b2f((uint32_t)ZS[(size_t)wid*64 + lane])*wa[lane];
        for (int o=32;o;o>>=1) v += __shfl_xor(v,o,64);
        if (lane==0) a_s[wid]=v;
    } else if (wid < 2*NE_N){
        int k = wid - NE_N;
        float v = b2f((uint32_t)E1[(size_t)k*128 + lane])*wv[lane]
                + b2f((uint32_t)E1[(size_t)k*128 + 64 + lane])*wv[64+lane];
        for (int o=32;o;o>>=1) v += __shfl_xor(v,o,64);
        if (lane==0) a_d[k]=v;
    }
}

// ================= prep =================
constexpr int WB_WSUM   = 0;
constexpr int WB_EEWL   = 16384;
constexpr int WB_EPWL   = 32768;
constexpr int WB_PEWL   = 49152;
constexpr int WB_EPWR1  = 65536;
constexpr int WB_LINE   = 81920;
constexpr int WB_LINP   = 90112;
constexpr int WB_GATW   = 94208;
constexpr int WB_S2EPWL = 102400;
constexpr int WB_S2PEWR = 110592;
constexpr int WB_S2PEWL = 118784;
constexpr int WB_S2EPWR = 126976;

__global__ void prep(const float* Wr_ee, const float* Wr_pe,
                     const float* ee_Wl, const float* ep_Wl, const float* pe_Wl, const float* ep_Wr,
                     const float* line_w, const float* linp_w,
                     const float* gatW, const float* s2epWl, const float* s2peWr,
                     const float* s2peWl, const float* s2epWr,
                     const float* bl_ee, const float* bl_pe,
                     const float* s2_pe_bl, const float* gat_b,
                     const float* Wdst, const float* adst,
                     uint16_t* wb, float* bsum1, float* b2sum, float* vvec)
{
    int j = blockIdx.x, t = threadIdx.x;
    if (j == 12){
        if (t < HD){
            bsum1[t] = bl_ee[t] + bl_pe[t];
            float s = 0.f;
            for (int c=0;c<OUTD;c++) s += Wdst[t*OUTD + c]*adst[c];
            vvec[t] = s;
        }
        if (t < OUTD) b2sum[t] = s2_pe_bl[t] + gat_b[t];
        return;
    }
    if (j == 0){
        for (int i=t; i<16384; i+=256) wb[WB_WSUM + i] = f2b(Wr_ee[i] + Wr_pe[i]);
        return;
    }
    const float* src; uint16_t* dst; int n;
    switch(j){
        case 1:  src=ee_Wl;  dst=wb+WB_EEWL;   n=16384; break;
        case 2:  src=ep_Wl;  dst=wb+WB_EPWL;   n=16384; break;
        case 3:  src=pe_Wl;  dst=wb+WB_PEWL;   n=16384; break;
        case 4:  src=ep_Wr;  dst=wb+WB_EPWR1;  n=16384; break;
        case 5:  src=line_w; dst=wb+WB_LINE;   n=8192;  break;
        case 6:  src=linp_w; dst=wb+WB_LINP;   n=4096;  break;
        case 7:  src=gatW;   dst=wb+WB_GATW;   n=8192;  break;
        case 8:  src=s2epWl; dst=wb+WB_S2EPWL; n=8192;  break;
        case 9:  src=s2peWr; dst=wb+WB_S2PEWR; n=8192;  break;
        case 10: src=s2peWl; dst=wb+WB_S2PEWL; n=8192;  break;
        default: src=s2epWr; dst=wb+WB_S2EPWR; n=8192;  break;
    }
    for (int i=t; i<n; i+=256) dst[i] = f2b(src[i]);
}

__global__ void convx(const float* __restrict__ xe, const float* __restrict__ xp,
                      uint16_t* __restrict__ be, uint16_t* __restrict__ bp){
    const int NE4 = NE_N*64/4, NP4 = NPER_N*32/4;
    int i = blockIdx.x*blockDim.x + threadIdx.x;
    if (i < NE4){
        v4fl v = __builtin_nontemporal_load(reinterpret_cast<const v4fl*>(xe + (size_t)i*4));
        uint2 o;
        o.x = (uint32_t)f2b(v.x) | ((uint32_t)f2b(v.y) << 16);
        o.y = (uint32_t)f2b(v.z) | ((uint32_t)f2b(v.w) << 16);
        *reinterpret_cast<uint2*>(&be[(size_t)i*4]) = o;
    } else if (i < NE4 + NP4){
        int k = i - NE4;
        v4fl v = __builtin_nontemporal_load(reinterpret_cast<const v4fl*>(xp + (size_t)k*4));
        uint2 o;
        o.x = (uint32_t)f2b(v.x) | ((uint32_t)f2b(v.y) << 16);
        o.y = (uint32_t)f2b(v.z) | ((uint32_t)f2b(v.w) << 16);
        *reinterpret_cast<uint2*>(&bp[(size_t)k*4]) = o;
    }
}

// ---------------- workspace layout (4B units) ----------------
constexpr size_t OFF_R0 = 0;          // xbe -> zsB
constexpr size_t OFF_R1 = 3200000;    // xbp -> p2peB
constexpr size_t OFF_R2 = 4800000;    // h_empB
constexpr size_t OFF_R3 = 11200000;   // h_perB
constexpr size_t OFF_R4 = 14400000;   // emp1B (6.4M) + per1B (@+6.4M, 3.2M)
constexpr size_t OFF_R5 = 27200000;   // p2epB (3.2M)
constexpr size_t OFF_R6 = 33600000;   // proj_eeB
constexpr size_t OFF_R7 = 40000000;   // proj_peB
constexpr size_t OFF_R8 = 43200000;   // proj_epB
constexpr size_t OFF_AS = 49600000;
constexpr size_t OFF_AD = 49700000;
constexpr size_t OFF_WB = 49800000;
constexpr size_t OFF_BS1= 49900000;
constexpr size_t OFF_BS2= 49900128;
constexpr size_t OFF_VV = 49900192;
constexpr size_t OFF_CNT    = 50000000;
constexpr size_t OFF_EE_OFF = 50250000;
constexpr size_t OFF_PE_OFF = 50350008;
constexpr size_t OFF_EP_OFF = 50450016;
constexpr size_t OFF_PART   = 50500024;
constexpr size_t OFF_EE_CSR = 50500416;
constexpr size_t OFF_PE_CSR = 52100416;
constexpr size_t OFF_EP_CSR = 52900416;

extern "C" void kernel_launch(void* const* d_in, const int* in_sizes, int n_in,
                              void* d_out, int out_size, void* d_ws, size_t ws_size,
                              hipStream_t stream)
{
    const float* x_emp = (const float*)d_in[0];
    const float* x_per = (const float*)d_in[1];
    const int* ee_src = (const int*)d_in[2];
    const int* ee_dst = (const int*)d_in[3];
    const int* pe_src = (const int*)d_in[4];
    const int* pe_dst = (const int*)d_in[5];
    const int* ep_src = (const int*)d_in[6];
    const int* ep_dst = (const int*)d_in[7];
    const float* lin_emp_w=(const float*)d_in[8],  *lin_emp_b=(const float*)d_in[9];
    const float* lin_per_w=(const float*)d_in[10], *lin_per_b=(const float*)d_in[11];
    const float* s1_ee_Wl=(const float*)d_in[12], *s1_ee_bl=(const float*)d_in[13], *s1_ee_Wr=(const float*)d_in[14];
    const float* s1_pe_Wl=(const float*)d_in[15], *s1_pe_bl=(const float*)d_in[16], *s1_pe_Wr=(const float*)d_in[17];
    const float* s1_ep_Wl=(const float*)d_in[18], *s1_ep_bl=(const float*)d_in[19], *s1_ep_Wr=(const float*)d_in[20];
    const float* gat_Wsrc=(const float*)d_in[21], *gat_Wdst=(const float*)d_in[22];
    const float* gat_asrc=(const float*)d_in[23], *gat_adst=(const float*)d_in[24], *gat_b=(const float*)d_in[25];
    const float* s2_pe_Wl=(const float*)d_in[26], *s2_pe_bl=(const float*)d_in[27], *s2_pe_Wr=(const float*)d_in[28];
    const float* s2_ep_Wl=(const float*)d_in[29], *s2_ep_bl=(const float*)d_in[30], *s2_ep_Wr=(const float*)d_in[31];

    float* ws = (float*)d_ws;
    int*   wi = (int*)d_ws;
    float* out_emp = (float*)d_out;
    float* out_per = out_emp + (size_t)NE_N*OUTD;

    uint16_t* xbe     = (uint16_t*)(ws + OFF_R0);
    uint16_t* zsB     = (uint16_t*)(ws + OFF_R0);
    uint16_t* xbp     = (uint16_t*)(ws + OFF_R1);
    uint16_t* p2peB   = (uint16_t*)(ws + OFF_R1);
    uint16_t* h_empB  = (uint16_t*)(ws + OFF_R2);
    uint16_t* h_perB  = (uint16_t*)(ws + OFF_R3);
    uint16_t* emp1B   = (uint16_t*)(ws + OFF_R4);
    uint16_t* per1B   = (uint16_t*)(ws + OFF_R4 + 6400000);
    uint16_t* p2epB   = (uint16_t*)(ws + OFF_R5);
    uint16_t* proj_eeB= (uint16_t*)(ws + OFF_R6);
    uint16_t* proj_peB= (uint16_t*)(ws + OFF_R7);
    uint16_t* proj_epB= (uint16_t*)(ws + OFF_R8);
    float* a_s   = ws + OFF_AS;
    float* a_d   = ws + OFF_AD;
    uint16_t* WB = (uint16_t*)(ws + OFF_WB);
    float* bsum1 = ws + OFF_BS1;
    float* b2sum = ws + OFF_BS2;
    float* vvec  = ws + OFF_VV;

    int* cnt_all = wi + OFF_CNT;
    int* ee_off = wi + OFF_EE_OFF; int* ee_csr = wi + OFF_EE_CSR;
    int* pe_off = wi + OFF_PE_OFF; int* pe_csr = wi + OFF_PE_CSR;
    int* ep_off = wi + OFF_EP_OFF; int* ep_csr = wi + OFF_EP_CSR;
    int* part   = wi + OFF_PART;

    const int GE = ceil_div(NE_N,256), GP = ceil_div(NPER_N,256);

    hipMemsetAsync(cnt_all, 0, 250000*sizeof(int), stream);

    prep<<<13,256,0,stream>>>(s1_ee_Wr, s1_pe_Wr, s1_ee_Wl, s1_ep_Wl, s1_pe_Wl, s1_ep_Wr,
                              lin_emp_w, lin_per_w,
                              gat_Wsrc, s2_ep_Wl, s2_pe_Wr, s2_pe_Wl, s2_ep_Wr,
                              s1_ee_bl, s1_pe_bl, s2_pe_bl, gat_b, gat_Wdst, gat_adst,
                              WB, bsum1, b2sum, vvec);
    convx<<<ceil_div(NE_N*64/4 + NPER_N*32/4, 256),256,0,stream>>>(x_emp, x_per, xbe, xbp);

    // ---- CSR build ----
    count_all<<<ceil_div(ETOT,256),256,0,stream>>>(ee_dst, pe_dst, ep_dst, cnt_all);
    scan_block3<<<dim3(ceil_div(NE_N,1024),3),256,0,stream>>>(cnt_all, ee_off, pe_off, ep_off, part);
    scan_partial3<<<3,64,0,stream>>>(part);
    add_base3<<<ceil_div(2*(NE_N+1)+NPER_N+1,256),256,0,stream>>>(ee_off, pe_off, ep_off, part);
    const int NCHUNK = ceil_div(ETOT,256);
    fill_sharded<<<NCHUNK*8,256,0,stream>>>(ee_src, ee_dst, pe_src, pe_dst, ep_src, ep_dst,
                                            ee_off, pe_off, ep_off, cnt_all,
                                            ee_csr, pe_csr, ep_csr);

    // ---- GEMMs ----
    {
        Segs g{};
        g.s[0] = Seg{WB+WB_LINE,    lin_emp_b,    (void*)h_empB,      128,128,2};
        g.s[1] = Seg{WB+WB_LINE+64, lin_emp_b+64, (void*)(h_empB+64), 128,128,2};
        g.s[2]=g.s[0]; g.s[3]=g.s[0]; g.s[4]=g.s[0]; g.s[5]=g.s[0];
        gemm_mfma<64><<<dim3(GE,2),256,0,stream>>>(xbe, NE_N, g);
    }
    {
        Segs g{};
        g.s[0] = Seg{WB+WB_LINP,    lin_per_b,    (void*)h_perB,      128,128,2};
        g.s[1] = Seg{WB+WB_LINP+64, lin_per_b+64, (void*)(h_perB+64), 128,128,2};
        g.s[2]=g.s[0]; g.s[3]=g.s[0]; g.s[4]=g.s[0]; g.s[5]=g.s[0];
        gemm_mfma<32><<<dim3(GP,2),256,0,stream>>>(xbp, NPER_N, g);
    }
    {   // conv1 from h_emp: emp1 base (bf16+bias), proj_ee, proj_ep
        Segs g{};
        g.s[0] = Seg{WB+WB_WSUM,    bsum1,    (void*)emp1B,        128,128,3};
        g.s[1] = Seg{WB+WB_WSUM+64, bsum1+64, (void*)(emp1B+64),   128,128,3};
        g.s[2] = Seg{WB+WB_EEWL,    nullptr,  (void*)proj_eeB,     128,128,1};
        g.s[3] = Seg{WB+WB_EEWL+64, nullptr,  (void*)(proj_eeB+64),128,128,1};
        g.s[4] = Seg{WB+WB_EPWL,    nullptr,  (void*)proj_epB,     128,128,1};
        g.s[5] = Seg{WB+WB_EPWL+64, nullptr,  (void*)(proj_epB+64),128,128,1};
        gemm_mfma<128><<<dim3(GE,6),256,0,stream>>>(h_empB, NE_N, g);
    }
    {   // conv1 from h_per: proj_pe, per1 base (bf16+bias)
        Segs g{};
        g.s[0] = Seg{WB+WB_PEWL,    nullptr,     (void*)proj_peB,     128,128,1};
        g.s[1] = Seg{WB+WB_PEWL+64, nullptr,     (void*)(proj_peB+64),128,128,1};
        g.s[2] = Seg{WB+WB_EPWR1,   s1_ep_bl,    (void*)per1B,        128,128,3};
        g.s[3] = Seg{WB+WB_EPWR1+64,s1_ep_bl+64, (void*)(per1B+64),   128,128,3};
        g.s[4]=g.s[0]; g.s[5]=g.s[0];
        gemm_mfma<128><<<dim3(GP,4),256,0,stream>>>(h_perB, NPER_N, g);
    }
    agg1_fused<<<ceil_div((long long)(NE_N+NPER_N)*64,256),256,0,stream>>>(
        proj_eeB, proj_peB, proj_epB, ee_off, ee_csr, pe_off, pe_csr, ep_off, ep_csr,
        emp1B, per1B);

    {   // conv2 from emp1
        Segs g{};
        g.s[0] = Seg{WB+WB_GATW,   nullptr, (void*)zsB,     64,64,1};
        g.s[1] = Seg{WB+WB_S2EPWL, nullptr, (void*)p2epB,   64,64,1};
        g.s[2] = Seg{WB+WB_S2PEWR, b2sum,   (void*)out_emp, 64,64,0};
        g.s[3]=g.s[0]; g.s[4]=g.s[0]; g.s[5]=g.s[0];
        gemm_mfma<128><<<dim3(GE,3),256,0,stream>>>(emp1B, NE_N, g);
    }
    rowdots<<<ceil_div(2*NE_N,4),256,0,stream>>>(zsB, emp1B, gat_asrc, vvec, a_s, a_d);
    {   // conv2 from per1
        Segs g{};
        g.s[0] = Seg{WB+WB_S2PEWL, nullptr,  (void*)p2peB,   64,64,1};
        g.s[1] = Seg{WB+WB_S2EPWR, s2_ep_bl, (void*)out_per, 64,64,0};
        g.s[2]=g.s[0]; g.s[3]=g.s[0]; g.s[4]=g.s[0]; g.s[5]=g.s[0];
        gemm_mfma<128><<<dim3(GP,2),256,0,stream>>>(per1B, NPER_N, g);
    }

    agg2_fused<<<ceil_div((long long)(NE_N+NPER_N)*64,256),256,0,stream>>>(
        ee_off, ee_csr, pe_off, pe_csr, ep_off, ep_csr, a_s, a_d,
        zsB, p2peB, p2epB, out_emp, out_per);
}

// Round 13
// 797.676 us; speedup vs baseline: 1.3582x; 1.3582x over previous
//
#include <hip/hip_runtime.h>
#include <cstdint>

#define NE_N   100000
#define NPER_N 50000
#define HD     128
#define OUTD   64
#define NEE    1600000
#define NPE    800000
#define NEP    800000
#define ETOT   (NEE+NPE+NEP)

static inline int ceil_div(long long a, long long b){ return (int)((a + b - 1)/b); }

__device__ __forceinline__ float4 ld4(const float* p){ return *reinterpret_cast<const float4*>(p); }
__device__ __forceinline__ void st4(float* p, float4 v){ *reinterpret_cast<float4*>(p) = v; }
__device__ __forceinline__ uint16_t f2b(float f){            // fp32 -> bf16 RNE
    uint32_t u = __float_as_uint(f);
    u += 0x7fffu + ((u >> 16) & 1u);
    return (uint16_t)(u >> 16);
}
__device__ __forceinline__ float b2f(uint32_t u){ return __uint_as_float(u << 16); }

typedef short v8s __attribute__((ext_vector_type(8)));
typedef float v4f __attribute__((ext_vector_type(4)));
typedef float v4fl __attribute__((ext_vector_type(4)));   // nt-loadable float4

// ================= MFMA bf16 GEMM =================
// mode: 0 = f32 out + bias ; 1 = bf16 out ; 2 = bf16 + bias + relu ; 3 = bf16 + bias
struct Seg { const uint16_t* W; const float* b; void* C; int ldw; int ldc; int mode; };
struct Segs { Seg s[6]; };

template<int K>
__global__ __launch_bounds__(256)
void gemm_mfma(const uint16_t* __restrict__ A, int N, Segs segs)
{
    constexpr int NKS  = K / 32;
    constexpr int PADK = K + 8;
    __shared__ __align__(16) uint16_t Wt[64 * PADK];

    Seg sg = segs.s[blockIdx.y];

    const int t = threadIdx.x;
    for (int i = t; i < K*64; i += 256){
        int k = i >> 6, c = i & 63;
        Wt[c*PADK + k] = sg.W[(size_t)k*sg.ldw + c];
    }
    __syncthreads();

    const int lane = t & 63, wid = t >> 6;
    const int l16 = lane & 15, lg = lane >> 4;
    const int rowbase = blockIdx.x*256 + wid*64;

    v4f acc[4][4];
#pragma unroll
    for (int i=0;i<4;i++)
#pragma unroll
        for (int j=0;j<4;j++) acc[i][j] = (v4f){0.f,0.f,0.f,0.f};

#pragma unroll
    for (int ks=0; ks<NKS; ks++){
        const int koff = ks*32 + lg*8;
        v8s a[4], b[4];
#pragma unroll
        for (int rt=0;rt<4;rt++){
            int r = rowbase + rt*16 + l16; if (r > N-1) r = N-1;
            a[rt] = *reinterpret_cast<const v8s*>(&A[(size_t)r*K + koff]);
        }
#pragma unroll
        for (int ct=0;ct<4;ct++)
            b[ct] = *reinterpret_cast<const v8s*>(&Wt[(ct*16 + l16)*PADK + koff]);
#pragma unroll
        for (int rt=0;rt<4;rt++)
#pragma unroll
            for (int ct=0;ct<4;ct++)
                acc[rt][ct] = __builtin_amdgcn_mfma_f32_16x16x32_bf16(a[rt], b[ct], acc[rt][ct], 0, 0, 0);
    }

    const int mode = sg.mode, ldc = sg.ldc;
    float bias[4];
    if (mode != 1){
#pragma unroll
        for (int ct=0;ct<4;ct++) bias[ct] = sg.b[ct*16 + l16];
    }
#pragma unroll
    for (int rt=0;rt<4;rt++){
#pragma unroll
        for (int rg=0;rg<4;rg++){
            int r = rowbase + rt*16 + lg*4 + rg;
            if (r < N){
#pragma unroll
                for (int ct=0;ct<4;ct++){
                    float v = acc[rt][ct][rg];
                    int c = ct*16 + l16;
                    if (mode == 0)
                        ((float*)sg.C)[(size_t)r*ldc + c] = v + bias[ct];
                    else if (mode == 1)
                        ((uint16_t*)sg.C)[(size_t)r*ldc + c] = f2b(v);
                    else if (mode == 2)
                        ((uint16_t*)sg.C)[(size_t)r*ldc + c] = f2b(fmaxf(v + bias[ct], 0.f));
                    else
                        ((uint16_t*)sg.C)[(size_t)r*ldc + c] = f2b(v + bias[ct]);
                }
            }
        }
    }
}

// ================= CSR build: XCD-sharded count/fill with nt edge reads =================
__global__ void count_sharded(const int* __restrict__ ee, const int* __restrict__ pe,
                              const int* __restrict__ ep, int* __restrict__ cnt){
    int r = blockIdx.x & 7;
    int i = (blockIdx.x >> 3)*256 + threadIdx.x;
    int d, base, n;
    if (i < NEE){ d = __builtin_nontemporal_load(&ee[i]); base = 0; n = NE_N; }
    else if (i < NEE+NPE){ d = __builtin_nontemporal_load(&pe[i-NEE]); base = 100000; n = NE_N; }
    else if (i < ETOT){ d = __builtin_nontemporal_load(&ep[i-NEE-NPE]); base = 200000; n = NPER_N; }
    else return;
    int seg = n >> 3;
    if (d >= r*seg && d < (r+1)*seg) atomicAdd(&cnt[base + d], 1);
}
__global__ __launch_bounds__(256)
void scan_block3(const int* __restrict__ cnt_all, int* __restrict__ ee_off,
                 int* __restrict__ pe_off, int* __restrict__ ep_off,
                 int* __restrict__ partial){
    int r = blockIdx.y;
    const int* cnt = cnt_all + (r==0 ? 0 : (r==1 ? 100000 : 200000));
    int* off = (r==0) ? ee_off : (r==1 ? pe_off : ep_off);
    int n = (r==2) ? NPER_N : NE_N;
    int* part = partial + r*128;

    __shared__ int sh[256];
    int t = threadIdx.x;
    int base = blockIdx.x*1024 + t*4;
    int v0 = (base  <n)?cnt[base  ]:0;
    int v1 = (base+1<n)?cnt[base+1]:0;
    int v2 = (base+2<n)?cnt[base+2]:0;
    int v3 = (base+3<n)?cnt[base+3]:0;
    int tsum = v0+v1+v2+v3;
    sh[t]=tsum; __syncthreads();
    for (int d=1; d<256; d<<=1){
        int x = (t>=d)? sh[t-d] : 0;
        __syncthreads();
        sh[t] += x;
        __syncthreads();
    }
    int ex = sh[t]-tsum;
    if (base  <n) off[base  ]=ex;
    if (base+1<n) off[base+1]=ex+v0;
    if (base+2<n) off[base+2]=ex+v0+v1;
    if (base+3<n) off[base+3]=ex+v0+v1+v2;
    if (t==255) part[blockIdx.x]=sh[255];
}
__global__ void scan_partial3(int* __restrict__ partial){
    int r = blockIdx.x;
    if (threadIdx.x != 0) return;
    int n = (r==2) ? NPER_N : NE_N;
    int nb = (n + 1023) >> 10;
    int* p = partial + r*128;
    int run = 0;
    for (int i=0;i<nb;i++){ int v=p[i]; p[i]=run; run+=v; }
}
__global__ void add_base3(int* __restrict__ ee_off, int* __restrict__ pe_off,
                          int* __restrict__ ep_off, const int* __restrict__ partial){
    int i = blockIdx.x*blockDim.x + threadIdx.x;
    if (i <= NE_N){
        if (i < NE_N) ee_off[i] += partial[i>>10];
        else ee_off[NE_N] = NEE;
    } else if (i <= 2*NE_N + 1){
        int k = i - (NE_N+1);
        if (k < NE_N) pe_off[k] += partial[128 + (k>>10)];
        else pe_off[NE_N] = NPE;
    } else {
        int k = i - 2*(NE_N+1);
        if (k < NPER_N) ep_off[k] += partial[256 + (k>>10)];
        else if (k == NPER_N) ep_off[NPER_N] = NEP;
    }
}
__global__ void fill_sharded(const int* __restrict__ ee_src, const int* __restrict__ ee_dst,
                             const int* __restrict__ pe_src, const int* __restrict__ pe_dst,
                             const int* __restrict__ ep_src, const int* __restrict__ ep_dst,
                             const int* __restrict__ ee_off, const int* __restrict__ pe_off,
                             const int* __restrict__ ep_off, int* __restrict__ cnt_all,
                             int* __restrict__ ee_csr, int* __restrict__ pe_csr,
                             int* __restrict__ ep_csr){
    int r = blockIdx.x & 7;
    int i = (blockIdx.x >> 3)*256 + threadIdx.x;
    int d, base, n;
    const int* srcp; const int* offp; int* csrp;
    if (i < NEE){ d = __builtin_nontemporal_load(&ee_dst[i]); base = 0; n = NE_N; srcp = ee_src; offp = ee_off; csrp = ee_csr; }
    else if (i < NEE+NPE){ i -= NEE; d = __builtin_nontemporal_load(&pe_dst[i]); base = 100000; n = NE_N; srcp = pe_src; offp = pe_off; csrp = pe_csr; }
    else if (i < ETOT){ i -= NEE+NPE; d = __builtin_nontemporal_load(&ep_dst[i]); base = 200000; n = NPER_N; srcp = ep_src; offp = ep_off; csrp = ep_csr; }
    else return;
    int seg = n >> 3;
    if (d >= r*seg && d < (r+1)*seg){
        int old = atomicAdd(&cnt_all[base + d], -1);
        csrp[offp[d] + old - 1] = __builtin_nontemporal_load(&srcp[i]);
    }
}

// ================= gather aggregation (round-10 proven structure; bf16 self) =================
__global__ __launch_bounds__(256)
void agg_emp1(const uint16_t* __restrict__ proj_ee, const uint16_t* __restrict__ proj_pe,
              const int* __restrict__ ee_off, const int* __restrict__ ee_csr,
              const int* __restrict__ pe_off, const int* __restrict__ pe_csr,
              uint16_t* __restrict__ emp1b){
    int w    = (blockIdx.x*blockDim.x + threadIdx.x) >> 6;
    int lane = threadIdx.x & 63;
    if (w >= NE_N) return;
    int grp = lane >> 4, l16 = lane & 15;

    float a[8] = {0,0,0,0,0,0,0,0};
    int b = ee_off[w], e = ee_off[w+1];
    int dee = e - b;
    for (int cb=b; cb<e; cb+=64){
        int j = cb + lane;
        int s = (j<e) ? ee_csr[j] : -1;
        int lim = e - cb; if (lim > 64) lim = 64;
        int iters = (lim + 3) >> 2;
        for (int k=0;k<iters;k++){
            int sg = __shfl(s, k*4 + grp, 64);
            if (sg >= 0){
                uint4 u = *reinterpret_cast<const uint4*>(&proj_ee[(size_t)sg*128 + l16*8]);
                a[0]+=b2f(u.x&0xffffu); a[1]+=b2f(u.x>>16);
                a[2]+=b2f(u.y&0xffffu); a[3]+=b2f(u.y>>16);
                a[4]+=b2f(u.z&0xffffu); a[5]+=b2f(u.z>>16);
                a[6]+=b2f(u.w&0xffffu); a[7]+=b2f(u.w>>16);
            }
        }
    }
    float c[8] = {0,0,0,0,0,0,0,0};
    b = pe_off[w]; e = pe_off[w+1];
    int dpe = e - b;
    for (int cb=b; cb<e; cb+=64){
        int j = cb + lane;
        int s = (j<e) ? pe_csr[j] : -1;
        int lim = e - cb; if (lim > 64) lim = 64;
        int iters = (lim + 3) >> 2;
        for (int k=0;k<iters;k++){
            int sg = __shfl(s, k*4 + grp, 64);
            if (sg >= 0){
                uint4 u = *reinterpret_cast<const uint4*>(&proj_pe[(size_t)sg*128 + l16*8]);
                c[0]+=b2f(u.x&0xffffu); c[1]+=b2f(u.x>>16);
                c[2]+=b2f(u.y&0xffffu); c[3]+=b2f(u.y>>16);
                c[4]+=b2f(u.z&0xffffu); c[5]+=b2f(u.z>>16);
                c[6]+=b2f(u.w&0xffffu); c[7]+=b2f(u.w>>16);
            }
        }
    }
#pragma unroll
    for (int f=0;f<8;f++){
        a[f] += __shfl_xor(a[f],16,64); a[f] += __shfl_xor(a[f],32,64);
        c[f] += __shfl_xor(c[f],16,64); c[f] += __shfl_xor(c[f],32,64);
    }
    if (grp == 0){
        float s1f = 1.f/fmaxf((float)dee,1.f);
        float s2f = 1.f/fmaxf((float)dpe,1.f);
        uint4 sb = *reinterpret_cast<const uint4*>(&emp1b[(size_t)w*128 + l16*8]);
        float sf[8] = { b2f(sb.x&0xffffu), b2f(sb.x>>16), b2f(sb.y&0xffffu), b2f(sb.y>>16),
                        b2f(sb.z&0xffffu), b2f(sb.z>>16), b2f(sb.w&0xffffu), b2f(sb.w>>16) };
        uint32_t o[8];
#pragma unroll
        for (int f=0;f<8;f++) o[f] = (uint32_t)f2b(fmaxf(sf[f] + a[f]*s1f + c[f]*s2f, 0.f));
        uint4 pk;
        pk.x = o[0] | (o[1]<<16); pk.y = o[2] | (o[3]<<16);
        pk.z = o[4] | (o[5]<<16); pk.w = o[6] | (o[7]<<16);
        *reinterpret_cast<uint4*>(&emp1b[(size_t)w*128 + l16*8]) = pk;
    }
}
__global__ __launch_bounds__(256)
void agg_per1(const uint16_t* __restrict__ proj_ep,
              const int* __restrict__ ep_off, const int* __restrict__ ep_csr,
              uint16_t* __restrict__ per1b){
    int w    = (blockIdx.x*blockDim.x + threadIdx.x) >> 6;
    int lane = threadIdx.x & 63;
    if (w >= NPER_N) return;
    int grp = lane >> 4, l16 = lane & 15;

    float a[8] = {0,0,0,0,0,0,0,0};
    int b = ep_off[w], e = ep_off[w+1];
    int deg = e - b;
    for (int cb=b; cb<e; cb+=64){
        int j = cb + lane;
        int s = (j<e) ? ep_csr[j] : -1;
        int lim = e - cb; if (lim > 64) lim = 64;
        int iters = (lim + 3) >> 2;
        for (int k=0;k<iters;k++){
            int sg = __shfl(s, k*4 + grp, 64);
            if (sg >= 0){
                uint4 u = *reinterpret_cast<const uint4*>(&proj_ep[(size_t)sg*128 + l16*8]);
                a[0]+=b2f(u.x&0xffffu); a[1]+=b2f(u.x>>16);
                a[2]+=b2f(u.y&0xffffu); a[3]+=b2f(u.y>>16);
                a[4]+=b2f(u.z&0xffffu); a[5]+=b2f(u.z>>16);
                a[6]+=b2f(u.w&0xffffu); a[7]+=b2f(u.w>>16);
            }
        }
    }
#pragma unroll
    for (int f=0;f<8;f++){
        a[f] += __shfl_xor(a[f],16,64); a[f] += __shfl_xor(a[f],32,64);
    }
    if (grp == 0){
        float s1f = 1.f/fmaxf((float)deg,1.f);
        uint4 sb = *reinterpret_cast<const uint4*>(&per1b[(size_t)w*128 + l16*8]);
        float sf[8] = { b2f(sb.x&0xffffu), b2f(sb.x>>16), b2f(sb.y&0xffffu), b2f(sb.y>>16),
                        b2f(sb.z&0xffffu), b2f(sb.z>>16), b2f(sb.w&0xffffu), b2f(sb.w>>16) };
        uint32_t o[8];
#pragma unroll
        for (int f=0;f<8;f++) o[f] = (uint32_t)f2b(fmaxf(sf[f] + a[f]*s1f, 0.f));
        uint4 pk;
        pk.x = o[0] | (o[1]<<16); pk.y = o[2] | (o[3]<<16);
        pk.z = o[4] | (o[5]<<16); pk.w = o[6] | (o[7]<<16);
        *reinterpret_cast<uint4*>(&per1b[(size_t)w*128 + l16*8]) = pk;
    }
}
__global__ __launch_bounds__(256)
void agg_per2(const uint16_t* __restrict__ p2ep,
              const int* __restrict__ ep_off, const int* __restrict__ ep_csr,
              float* __restrict__ out){
    int w    = (blockIdx.x*blockDim.x + threadIdx.x) >> 6;
    int lane = threadIdx.x & 63;
    if (w >= NPER_N) return;
    int grp = lane >> 4, l16 = lane & 15;

    float a[4] = {0,0,0,0};
    int b = ep_off[w], e = ep_off[w+1];
    int deg = e - b;
    for (int cb=b; cb<e; cb+=64){
        int j = cb + lane;
        int s = (j<e) ? ep_csr[j] : -1;
        int lim = e - cb; if (lim > 64) lim = 64;
        int iters = (lim + 3) >> 2;
        for (int k=0;k<iters;k++){
            int sg = __shfl(s, k*4 + grp, 64);
            if (sg >= 0){
                uint2 u = *reinterpret_cast<const uint2*>(&p2ep[(size_t)sg*64 + l16*4]);
                a[0]+=b2f(u.x&0xffffu); a[1]+=b2f(u.x>>16);
                a[2]+=b2f(u.y&0xffffu); a[3]+=b2f(u.y>>16);
            }
        }
    }
#pragma unroll
    for (int f=0;f<4;f++){
        a[f] += __shfl_xor(a[f],16,64); a[f] += __shfl_xor(a[f],32,64);
    }
    if (grp == 0){
        float s1f = 1.f/fmaxf((float)deg,1.f);
        float4 o4 = ld4(&out[(size_t)w*64 + l16*4]);
        o4.x += a[0]*s1f; o4.y += a[1]*s1f; o4.z += a[2]*s1f; o4.w += a[3]*s1f;
        st4(&out[(size_t)w*64 + l16*4], o4);
    }
}
__global__ __launch_bounds__(256)
void gat_sage_emp2(const int* __restrict__ ee_off, const int* __restrict__ ee_csr,
                   const int* __restrict__ pe_off, const int* __restrict__ pe_csr,
                   const float* __restrict__ as, const float* __restrict__ ad,
                   const uint16_t* __restrict__ zs, const uint16_t* __restrict__ p2pe,
                   float* __restrict__ out){
    int w    = (blockIdx.x*blockDim.x + threadIdx.x) >> 6;
    int lane = threadIdx.x & 63;
    if (w >= NE_N) return;
    int grp = lane >> 4, l16 = lane & 15;

    float g[4] = {0,0,0,0};
    float invden = 0.f;
    int b = ee_off[w], e = ee_off[w+1];
    if (e > b){
        float add = ad[w];
        float m = -INFINITY;
        for (int j=b+lane; j<e; j+=64){
            float ev = as[ee_csr[j]] + add;
            ev = ev > 0.f ? ev : 0.2f*ev;
            m = fmaxf(m, ev);
        }
        for (int o=32;o;o>>=1) m = fmaxf(m, __shfl_xor(m,o,64));

        float den = 0.f;
        for (int cb=b; cb<e; cb+=64){
            int j = cb + lane;
            int s = 0; float ex = 0.f;
            if (j < e){
                s = ee_csr[j];
                float ev = as[s] + add;
                ev = ev > 0.f ? ev : 0.2f*ev;
                ex = expf(ev - m);
            }
            den += ex;
            int lim = e - cb; if (lim > 64) lim = 64;
            int iters = (lim + 3) >> 2;
            for (int k=0;k<iters;k++){
                int   sg = __shfl(s,  k*4 + grp, 64);
                float ag = __shfl(ex, k*4 + grp, 64);
                uint2 u = *reinterpret_cast<const uint2*>(&zs[(size_t)sg*64 + l16*4]);
                g[0] += ag*b2f(u.x&0xffffu); g[1] += ag*b2f(u.x>>16);
                g[2] += ag*b2f(u.y&0xffffu); g[3] += ag*b2f(u.y>>16);
            }
        }
        for (int o=32;o;o>>=1) den += __shfl_xor(den,o,64);
        invden = 1.f/den;
    }

    float p[4] = {0,0,0,0};
    b = pe_off[w]; e = pe_off[w+1];
    int deg = e - b;
    for (int cb=b; cb<e; cb+=64){
        int j = cb + lane;
        int s = (j<e) ? pe_csr[j] : -1;
        int lim = e - cb; if (lim > 64) lim = 64;
        int iters = (lim + 3) >> 2;
        for (int k=0;k<iters;k++){
            int sg = __shfl(s, k*4 + grp, 64);
            if (sg >= 0){
                uint2 u = *reinterpret_cast<const uint2*>(&p2pe[(size_t)sg*64 + l16*4]);
                p[0]+=b2f(u.x&0xffffu); p[1]+=b2f(u.x>>16);
                p[2]+=b2f(u.y&0xffffu); p[3]+=b2f(u.y>>16);
            }
        }
    }
#pragma unroll
    for (int f=0;f<4;f++){
        g[f] += __shfl_xor(g[f],16,64); g[f] += __shfl_xor(g[f],32,64);
        p[f] += __shfl_xor(p[f],16,64); p[f] += __shfl_xor(p[f],32,64);
    }
    if (grp == 0){
        float s2f = 1.f/fmaxf((float)deg,1.f);
        float4 o4 = ld4(&out[(size_t)w*64 + l16*4]);
        o4.x += g[0]*invden + p[0]*s2f;
        o4.y += g[1]*invden + p[1]*s2f;
        o4.z += g[2]*invden + p[2]*s2f;
        o4.w += g[3]*invden + p[3]*s2f;
        st4(&out[(size_t)w*64 + l16*4], o4);
    }
}

__global__ void rowdots(const uint16_t* __restrict__ ZS, const uint16_t* __restrict__ E1,
                        const float* __restrict__ wa, const float* __restrict__ wv,
                        float* __restrict__ a_s, float* __restrict__ a_d){
    int wid  = (blockIdx.x*blockDim.x + threadIdx.x) >> 6;
    int lane = threadIdx.x & 63;
    if (wid < NE_N){
        float v = b2f((uint32_t)ZS[(size_t)wid*64 + lane])*wa[lane];
        for (int o=32;o;o>>=1) v += __shfl_xor(v,o,64);
        if (lane==0) a_s[wid]=v;
    } else if (wid < 2*NE_N){
        int k = wid - NE_N;
        float v = b2f((uint32_t)E1[(size_t)k*128 + lane])*wv[lane]
                + b2f((uint32_t)E1[(size_t)k*128 + 64 + lane])*wv[64+lane];
        for (int o=32;o;o>>=1) v += __shfl_xor(v,o,64);
        if (lane==0) a_d[k]=v;
    }
}

// ================= prep =================
constexpr int WB_WSUM   = 0;
constexpr int WB_EEWL   = 16384;
constexpr int WB_EPWL   = 32768;
constexpr int WB_PEWL   = 49152;
constexpr int WB_EPWR1  = 65536;
constexpr int WB_LINE   = 81920;
constexpr int WB_LINP   = 90112;
constexpr int WB_GATW   = 94208;
constexpr int WB_S2EPWL = 102400;
constexpr int WB_S2PEWR = 110592;
constexpr int WB_S2PEWL = 118784;
constexpr int WB_S2EPWR = 126976;

__global__ void prep(const float* Wr_ee, const float* Wr_pe,
                     const float* ee_Wl, const float* ep_Wl, const float* pe_Wl, const float* ep_Wr,
                     const float* line_w, const float* linp_w,
                     const float* gatW, const float* s2epWl, const float* s2peWr,
                     const float* s2peWl, const float* s2epWr,
                     const float* bl_ee, const float* bl_pe,
                     const float* s2_pe_bl, const float* gat_b,
                     const float* Wdst, const float* adst,
                     uint16_t* wb, float* bsum1, float* b2sum, float* vvec)
{
    int j = blockIdx.x, t = threadIdx.x;
    if (j == 12){
        if (t < HD){
            bsum1[t] = bl_ee[t] + bl_pe[t];
            float s = 0.f;
            for (int c=0;c<OUTD;c++) s += Wdst[t*OUTD + c]*adst[c];
            vvec[t] = s;
        }
        if (t < OUTD) b2sum[t] = s2_pe_bl[t] + gat_b[t];
        return;
    }
    if (j == 0){
        for (int i=t; i<16384; i+=256) wb[WB_WSUM + i] = f2b(Wr_ee[i] + Wr_pe[i]);
        return;
    }
    const float* src; uint16_t* dst; int n;
    switch(j){
        case 1:  src=ee_Wl;  dst=wb+WB_EEWL;   n=16384; break;
        case 2:  src=ep_Wl;  dst=wb+WB_EPWL;   n=16384; break;
        case 3:  src=pe_Wl;  dst=wb+WB_PEWL;   n=16384; break;
        case 4:  src=ep_Wr;  dst=wb+WB_EPWR1;  n=16384; break;
        case 5:  src=line_w; dst=wb+WB_LINE;   n=8192;  break;
        case 6:  src=linp_w; dst=wb+WB_LINP;   n=4096;  break;
        case 7:  src=gatW;   dst=wb+WB_GATW;   n=8192;  break;
        case 8:  src=s2epWl; dst=wb+WB_S2EPWL; n=8192;  break;
        case 9:  src=s2peWr; dst=wb+WB_S2PEWR; n=8192;  break;
        case 10: src=s2peWl; dst=wb+WB_S2PEWL; n=8192;  break;
        default: src=s2epWr; dst=wb+WB_S2EPWR; n=8192;  break;
    }
    for (int i=t; i<n; i+=256) dst[i] = f2b(src[i]);
}

__global__ void convx(const float* __restrict__ xe, const float* __restrict__ xp,
                      uint16_t* __restrict__ be, uint16_t* __restrict__ bp){
    const int NE4 = NE_N*64/4, NP4 = NPER_N*32/4;
    int i = blockIdx.x*blockDim.x + threadIdx.x;
    if (i < NE4){
        v4fl v = __builtin_nontemporal_load(reinterpret_cast<const v4fl*>(xe + (size_t)i*4));
        uint2 o;
        o.x = (uint32_t)f2b(v.x) | ((uint32_t)f2b(v.y) << 16);
        o.y = (uint32_t)f2b(v.z) | ((uint32_t)f2b(v.w) << 16);
        *reinterpret_cast<uint2*>(&be[(size_t)i*4]) = o;
    } else if (i < NE4 + NP4){
        int k = i - NE4;
        v4fl v = __builtin_nontemporal_load(reinterpret_cast<const v4fl*>(xp + (size_t)k*4));
        uint2 o;
        o.x = (uint32_t)f2b(v.x) | ((uint32_t)f2b(v.y) << 16);
        o.y = (uint32_t)f2b(v.z) | ((uint32_t)f2b(v.w) << 16);
        *reinterpret_cast<uint2*>(&bp[(size_t)k*4]) = o;
    }
}

// ---------------- workspace layout (4B units) ----------------
constexpr size_t OFF_R0 = 0;          // xbe -> zsB
constexpr size_t OFF_R1 = 3200000;    // xbp -> p2peB
constexpr size_t OFF_R2 = 4800000;    // h_empB
constexpr size_t OFF_R3 = 11200000;   // h_perB
constexpr size_t OFF_R4 = 14400000;   // emp1B (6.4M) + per1B (@+6.4M, 3.2M)
constexpr size_t OFF_R5 = 27200000;   // p2epB (3.2M)
constexpr size_t OFF_R6 = 33600000;   // proj_eeB
constexpr size_t OFF_R7 = 40000000;   // proj_peB
constexpr size_t OFF_R8 = 43200000;   // proj_epB
constexpr size_t OFF_AS = 49600000;
constexpr size_t OFF_AD = 49700000;
constexpr size_t OFF_WB = 49800000;
constexpr size_t OFF_BS1= 49900000;
constexpr size_t OFF_BS2= 49900128;
constexpr size_t OFF_VV = 49900192;
constexpr size_t OFF_CNT    = 50000000;
constexpr size_t OFF_EE_OFF = 50250000;
constexpr size_t OFF_PE_OFF = 50350008;
constexpr size_t OFF_EP_OFF = 50450016;
constexpr size_t OFF_PART   = 50500024;
constexpr size_t OFF_EE_CSR = 50500416;
constexpr size_t OFF_PE_CSR = 52100416;
constexpr size_t OFF_EP_CSR = 52900416;

extern "C" void kernel_launch(void* const* d_in, const int* in_sizes, int n_in,
                              void* d_out, int out_size, void* d_ws, size_t ws_size,
                              hipStream_t stream)
{
    const float* x_emp = (const float*)d_in[0];
    const float* x_per = (const float*)d_in[1];
    const int* ee_src = (const int*)d_in[2];
    const int* ee_dst = (const int*)d_in[3];
    const int* pe_src = (const int*)d_in[4];
    const int* pe_dst = (const int*)d_in[5];
    const int* ep_src = (const int*)d_in[6];
    const int* ep_dst = (const int*)d_in[7];
    const float* lin_emp_w=(const float*)d_in[8],  *lin_emp_b=(const float*)d_in[9];
    const float* lin_per_w=(const float*)d_in[10], *lin_per_b=(const float*)d_in[11];
    const float* s1_ee_Wl=(const float*)d_in[12], *s1_ee_bl=(const float*)d_in[13], *s1_ee_Wr=(const float*)d_in[14];
    const float* s1_pe_Wl=(const float*)d_in[15], *s1_pe_bl=(const float*)d_in[16], *s1_pe_Wr=(const float*)d_in[17];
    const float* s1_ep_Wl=(const float*)d_in[18], *s1_ep_bl=(const float*)d_in[19], *s1_ep_Wr=(const float*)d_in[20];
    const float* gat_Wsrc=(const float*)d_in[21], *gat_Wdst=(const float*)d_in[22];
    const float* gat_asrc=(const float*)d_in[23], *gat_adst=(const float*)d_in[24], *gat_b=(const float*)d_in[25];
    const float* s2_pe_Wl=(const float*)d_in[26], *s2_pe_bl=(const float*)d_in[27], *s2_pe_Wr=(const float*)d_in[28];
    const float* s2_ep_Wl=(const float*)d_in[29], *s2_ep_bl=(const float*)d_in[30], *s2_ep_Wr=(const float*)d_in[31];

    float* ws = (float*)d_ws;
    int*   wi = (int*)d_ws;
    float* out_emp = (float*)d_out;
    float* out_per = out_emp + (size_t)NE_N*OUTD;

    uint16_t* xbe     = (uint16_t*)(ws + OFF_R0);
    uint16_t* zsB     = (uint16_t*)(ws + OFF_R0);
    uint16_t* xbp     = (uint16_t*)(ws + OFF_R1);
    uint16_t* p2peB   = (uint16_t*)(ws + OFF_R1);
    uint16_t* h_empB  = (uint16_t*)(ws + OFF_R2);
    uint16_t* h_perB  = (uint16_t*)(ws + OFF_R3);
    uint16_t* emp1B   = (uint16_t*)(ws + OFF_R4);
    uint16_t* per1B   = (uint16_t*)(ws + OFF_R4 + 6400000);
    uint16_t* p2epB   = (uint16_t*)(ws + OFF_R5);
    uint16_t* proj_eeB= (uint16_t*)(ws + OFF_R6);
    uint16_t* proj_peB= (uint16_t*)(ws + OFF_R7);
    uint16_t* proj_epB= (uint16_t*)(ws + OFF_R8);
    float* a_s   = ws + OFF_AS;
    float* a_d   = ws + OFF_AD;
    uint16_t* WB = (uint16_t*)(ws + OFF_WB);
    float* bsum1 = ws + OFF_BS1;
    float* b2sum = ws + OFF_BS2;
    float* vvec  = ws + OFF_VV;

    int* cnt_all = wi + OFF_CNT;
    int* ee_off = wi + OFF_EE_OFF; int* ee_csr = wi + OFF_EE_CSR;
    int* pe_off = wi + OFF_PE_OFF; int* pe_csr = wi + OFF_PE_CSR;
    int* ep_off = wi + OFF_EP_OFF; int* ep_csr = wi + OFF_EP_CSR;
    int* part   = wi + OFF_PART;

    const int GE = ceil_div(NE_N,256), GP = ceil_div(NPER_N,256);

    hipMemsetAsync(cnt_all, 0, 250000*sizeof(int), stream);

    prep<<<13,256,0,stream>>>(s1_ee_Wr, s1_pe_Wr, s1_ee_Wl, s1_ep_Wl, s1_pe_Wl, s1_ep_Wr,
                              lin_emp_w, lin_per_w,
                              gat_Wsrc, s2_ep_Wl, s2_pe_Wr, s2_pe_Wl, s2_ep_Wr,
                              s1_ee_bl, s1_pe_bl, s2_pe_bl, gat_b, gat_Wdst, gat_adst,
                              WB, bsum1, b2sum, vvec);
    convx<<<ceil_div(NE_N*64/4 + NPER_N*32/4, 256),256,0,stream>>>(x_emp, x_per, xbe, xbp);

    // ---- CSR build: XCD-sharded count/fill with nt edge reads ----
    const int NCHUNK = ceil_div(ETOT,256);
    count_sharded<<<NCHUNK*8,256,0,stream>>>(ee_dst, pe_dst, ep_dst, cnt_all);
    scan_block3<<<dim3(ceil_div(NE_N,1024),3),256,0,stream>>>(cnt_all, ee_off, pe_off, ep_off, part);
    scan_partial3<<<3,64,0,stream>>>(part);
    add_base3<<<ceil_div(2*(NE_N+1)+NPER_N+1,256),256,0,stream>>>(ee_off, pe_off, ep_off, part);
    fill_sharded<<<NCHUNK*8,256,0,stream>>>(ee_src, ee_dst, pe_src, pe_dst, ep_src, ep_dst,
                                            ee_off, pe_off, ep_off, cnt_all,
                                            ee_csr, pe_csr, ep_csr);

    // ---- GEMMs ----
    {
        Segs g{};
        g.s[0] = Seg{WB+WB_LINE,    lin_emp_b,    (void*)h_empB,      128,128,2};
        g.s[1] = Seg{WB+WB_LINE+64, lin_emp_b+64, (void*)(h_empB+64), 128,128,2};
        g.s[2]=g.s[0]; g.s[3]=g.s[0]; g.s[4]=g.s[0]; g.s[5]=g.s[0];
        gemm_mfma<64><<<dim3(GE,2),256,0,stream>>>(xbe, NE_N, g);
    }
    {
        Segs g{};
        g.s[0] = Seg{WB+WB_LINP,    lin_per_b,    (void*)h_perB,      128,128,2};
        g.s[1] = Seg{WB+WB_LINP+64, lin_per_b+64, (void*)(h_perB+64), 128,128,2};
        g.s[2]=g.s[0]; g.s[3]=g.s[0]; g.s[4]=g.s[0]; g.s[5]=g.s[0];
        gemm_mfma<32><<<dim3(GP,2),256,0,stream>>>(xbp, NPER_N, g);
    }
    {   // conv1 from h_emp: emp1 base (bf16+bias), proj_ee, proj_ep
        Segs g{};
        g.s[0] = Seg{WB+WB_WSUM,    bsum1,    (void*)emp1B,        128,128,3};
        g.s[1] = Seg{WB+WB_WSUM+64, bsum1+64, (void*)(emp1B+64),   128,128,3};
        g.s[2] = Seg{WB+WB_EEWL,    nullptr,  (void*)proj_eeB,     128,128,1};
        g.s[3] = Seg{WB+WB_EEWL+64, nullptr,  (void*)(proj_eeB+64),128,128,1};
        g.s[4] = Seg{WB+WB_EPWL,    nullptr,  (void*)proj_epB,     128,128,1};
        g.s[5] = Seg{WB+WB_EPWL+64, nullptr,  (void*)(proj_epB+64),128,128,1};
        gemm_mfma<128><<<dim3(GE,6),256,0,stream>>>(h_empB, NE_N, g);
    }
    {   // conv1 from h_per: proj_pe, per1 base (bf16+bias)
        Segs g{};
        g.s[0] = Seg{WB+WB_PEWL,    nullptr,     (void*)proj_peB,     128,128,1};
        g.s[1] = Seg{WB+WB_PEWL+64, nullptr,     (void*)(proj_peB+64),128,128,1};
        g.s[2] = Seg{WB+WB_EPWR1,   s1_ep_bl,    (void*)per1B,        128,128,3};
        g.s[3] = Seg{WB+WB_EPWR1+64,s1_ep_bl+64, (void*)(per1B+64),   128,128,3};
        g.s[4]=g.s[0]; g.s[5]=g.s[0];
        gemm_mfma<128><<<dim3(GP,4),256,0,stream>>>(h_perB, NPER_N, g);
    }
    agg_emp1<<<ceil_div((long long)NE_N*64,256),256,0,stream>>>(proj_eeB, proj_peB, ee_off, ee_csr, pe_off, pe_csr, emp1B);
    agg_per1<<<ceil_div((long long)NPER_N*64,256),256,0,stream>>>(proj_epB, ep_off, ep_csr, per1B);

    {   // conv2 from emp1
        Segs g{};
        g.s[0] = Seg{WB+WB_GATW,   nullptr, (void*)zsB,     64,64,1};
        g.s[1] = Seg{WB+WB_S2EPWL, nullptr, (void*)p2epB,   64,64,1};
        g.s[2] = Seg{WB+WB_S2PEWR, b2sum,   (void*)out_emp, 64,64,0};
        g.s[3]=g.s[0]; g.s[4]=g.s[0]; g.s[5]=g.s[0];
        gemm_mfma<128><<<dim3(GE,3),256,0,stream>>>(emp1B, NE_N, g);
    }
    rowdots<<<ceil_div(2*NE_N,4),256,0,stream>>>(zsB, emp1B, gat_asrc, vvec, a_s, a_d);
    {   // conv2 from per1
        Segs g{};
        g.s[0] = Seg{WB+WB_S2PEWL, nullptr,  (void*)p2peB,   64,64,1};
        g.s[1] = Seg{WB+WB_S2EPWR, s2_ep_bl, (void*)out_per, 64,64,0};
        g.s[2]=g.s[0]; g.s[3]=g.s[0]; g.s[4]=g.s[0]; g.s[5]=g.s[0];
        gemm_mfma<128><<<dim3(GP,2),256,0,stream>>>(per1B, NPER_N, g);
    }

    gat_sage_emp2<<<ceil_div((long long)NE_N*64,256),256,0,stream>>>(ee_off, ee_csr, pe_off, pe_csr, a_s, a_d, zsB, p2peB, out_emp);
    agg_per2<<<ceil_div((long long)NPER_N*64,256),256,0,stream>>>(p2epB, ep_off, ep_csr, out_per);
}

// Round 14
// 747.110 us; speedup vs baseline: 1.4501x; 1.0677x over previous
//
#include <hip/hip_runtime.h>
#include <cstdint>

#define NE_N   100000
#define NPER_N 50000
#define HD     128
#define OUTD   64
#define NEE    1600000
#define NPE    800000
#define NEP    800000
#define ETOT   (NEE+NPE+NEP)

static inline int ceil_div(long long a, long long b){ return (int)((a + b - 1)/b); }

__device__ __forceinline__ float4 ld4(const float* p){ return *reinterpret_cast<const float4*>(p); }
__device__ __forceinline__ void st4(float* p, float4 v){ *reinterpret_cast<float4*>(p) = v; }
__device__ __forceinline__ uint16_t f2b(float f){            // fp32 -> bf16 RNE
    uint32_t u = __float_as_uint(f);
    u += 0x7fffu + ((u >> 16) & 1u);
    return (uint16_t)(u >> 16);
}
__device__ __forceinline__ float b2f(uint32_t u){ return __uint_as_float(u << 16); }

typedef short v8s __attribute__((ext_vector_type(8)));
typedef float v4f __attribute__((ext_vector_type(4)));
typedef float v4fl __attribute__((ext_vector_type(4)));   // nt-loadable float4

// ================= MFMA bf16 GEMM =================
// mode: 0 = f32 out + bias ; 1 = bf16 out ; 2 = bf16 + bias + relu ; 3 = bf16 + bias
//       4 = bf16 out + fused row-dot with aux -> auxout  (a_s = zs @ asrc)
struct Seg { const uint16_t* W; const float* b; void* C;
             const float* aux; float* auxout; int ldw; int ldc; int mode; };
struct Segs { Seg s[6]; };

template<int K>
__global__ __launch_bounds__(256)
void gemm_mfma(const uint16_t* __restrict__ A, int N, Segs segs)
{
    constexpr int NKS  = K / 32;
    constexpr int PADK = K + 8;
    __shared__ __align__(16) uint16_t Wt[64 * PADK];

    Seg sg = segs.s[blockIdx.y];

    const int t = threadIdx.x;
    for (int i = t; i < K*64; i += 256){
        int k = i >> 6, c = i & 63;
        Wt[c*PADK + k] = sg.W[(size_t)k*sg.ldw + c];
    }
    __syncthreads();

    const int lane = t & 63, wid = t >> 6;
    const int l16 = lane & 15, lg = lane >> 4;
    const int rowbase = blockIdx.x*256 + wid*64;

    v4f acc[4][4];
#pragma unroll
    for (int i=0;i<4;i++)
#pragma unroll
        for (int j=0;j<4;j++) acc[i][j] = (v4f){0.f,0.f,0.f,0.f};

#pragma unroll
    for (int ks=0; ks<NKS; ks++){
        const int koff = ks*32 + lg*8;
        v8s a[4], b[4];
#pragma unroll
        for (int rt=0;rt<4;rt++){
            int r = rowbase + rt*16 + l16; if (r > N-1) r = N-1;
            a[rt] = *reinterpret_cast<const v8s*>(&A[(size_t)r*K + koff]);
        }
#pragma unroll
        for (int ct=0;ct<4;ct++)
            b[ct] = *reinterpret_cast<const v8s*>(&Wt[(ct*16 + l16)*PADK + koff]);
#pragma unroll
        for (int rt=0;rt<4;rt++)
#pragma unroll
            for (int ct=0;ct<4;ct++)
                acc[rt][ct] = __builtin_amdgcn_mfma_f32_16x16x32_bf16(a[rt], b[ct], acc[rt][ct], 0, 0, 0);
    }

    const int mode = sg.mode, ldc = sg.ldc;
    float bias[4];
    if (mode == 0 || mode == 2 || mode == 3){
#pragma unroll
        for (int ct=0;ct<4;ct++) bias[ct] = sg.b[ct*16 + l16];
    }
    float aux[4];
    if (mode == 4){
#pragma unroll
        for (int ct=0;ct<4;ct++) aux[ct] = sg.aux[ct*16 + l16];
    }
#pragma unroll
    for (int rt=0;rt<4;rt++){
#pragma unroll
        for (int rg=0;rg<4;rg++){
            int r = rowbase + rt*16 + lg*4 + rg;
            bool valid = (r < N);
            float partial = 0.f;
            if (valid){
#pragma unroll
                for (int ct=0;ct<4;ct++){
                    float v = acc[rt][ct][rg];
                    int c = ct*16 + l16;
                    if (mode == 0)
                        ((float*)sg.C)[(size_t)r*ldc + c] = v + bias[ct];
                    else if (mode == 1)
                        ((uint16_t*)sg.C)[(size_t)r*ldc + c] = f2b(v);
                    else if (mode == 2)
                        ((uint16_t*)sg.C)[(size_t)r*ldc + c] = f2b(fmaxf(v + bias[ct], 0.f));
                    else if (mode == 3)
                        ((uint16_t*)sg.C)[(size_t)r*ldc + c] = f2b(v + bias[ct]);
                    else {
                        ((uint16_t*)sg.C)[(size_t)r*ldc + c] = f2b(v);
                        partial += v*aux[ct];
                    }
                }
            }
            if (mode == 4){
                partial += __shfl_xor(partial,1,64);
                partial += __shfl_xor(partial,2,64);
                partial += __shfl_xor(partial,4,64);
                partial += __shfl_xor(partial,8,64);
                if (valid && l16 == 0) sg.auxout[r] = partial;
            }
        }
    }
}

// ================= CSR build =================
__global__ void count_all(const int* __restrict__ ee, const int* __restrict__ pe,
                          const int* __restrict__ ep, int* __restrict__ cnt){
    int i = blockIdx.x*blockDim.x + threadIdx.x;
    if (i < NEE) atomicAdd(&cnt[__builtin_nontemporal_load(&ee[i])], 1);
    else if (i < NEE+NPE) atomicAdd(&cnt[100000 + __builtin_nontemporal_load(&pe[i-NEE])], 1);
    else if (i < ETOT) atomicAdd(&cnt[200000 + __builtin_nontemporal_load(&ep[i-NEE-NPE])], 1);
}
__global__ __launch_bounds__(256)
void scan_block3(const int* __restrict__ cnt_all, int* __restrict__ ee_off,
                 int* __restrict__ pe_off, int* __restrict__ ep_off,
                 int* __restrict__ partial){
    int r = blockIdx.y;
    const int* cnt = cnt_all + (r==0 ? 0 : (r==1 ? 100000 : 200000));
    int* off = (r==0) ? ee_off : (r==1 ? pe_off : ep_off);
    int n = (r==2) ? NPER_N : NE_N;
    int* part = partial + r*128;

    __shared__ int sh[256];
    int t = threadIdx.x;
    int base = blockIdx.x*1024 + t*4;
    int v0 = (base  <n)?cnt[base  ]:0;
    int v1 = (base+1<n)?cnt[base+1]:0;
    int v2 = (base+2<n)?cnt[base+2]:0;
    int v3 = (base+3<n)?cnt[base+3]:0;
    int tsum = v0+v1+v2+v3;
    sh[t]=tsum; __syncthreads();
    for (int d=1; d<256; d<<=1){
        int x = (t>=d)? sh[t-d] : 0;
        __syncthreads();
        sh[t] += x;
        __syncthreads();
    }
    int ex = sh[t]-tsum;
    if (base  <n) off[base  ]=ex;
    if (base+1<n) off[base+1]=ex+v0;
    if (base+2<n) off[base+2]=ex+v0+v1;
    if (base+3<n) off[base+3]=ex+v0+v1+v2;
    if (t==255) part[blockIdx.x]=sh[255];
}
__global__ void scan_partial3(int* __restrict__ partial){
    int r = blockIdx.x;
    if (threadIdx.x != 0) return;
    int n = (r==2) ? NPER_N : NE_N;
    int nb = (n + 1023) >> 10;
    int* p = partial + r*128;
    int run = 0;
    for (int i=0;i<nb;i++){ int v=p[i]; p[i]=run; run+=v; }
}
__global__ void add_base3(int* __restrict__ ee_off, int* __restrict__ pe_off,
                          int* __restrict__ ep_off, const int* __restrict__ partial){
    int i = blockIdx.x*blockDim.x + threadIdx.x;
    if (i <= NE_N){
        if (i < NE_N) ee_off[i] += partial[i>>10];
        else ee_off[NE_N] = NEE;
    } else if (i <= 2*NE_N + 1){
        int k = i - (NE_N+1);
        if (k < NE_N) pe_off[k] += partial[128 + (k>>10)];
        else pe_off[NE_N] = NPE;
    } else {
        int k = i - 2*(NE_N+1);
        if (k < NPER_N) ep_off[k] += partial[256 + (k>>10)];
        else if (k == NPER_N) ep_off[NPER_N] = NEP;
    }
}
__global__ void fill_sharded(const int* __restrict__ ee_src, const int* __restrict__ ee_dst,
                             const int* __restrict__ pe_src, const int* __restrict__ pe_dst,
                             const int* __restrict__ ep_src, const int* __restrict__ ep_dst,
                             const int* __restrict__ ee_off, const int* __restrict__ pe_off,
                             const int* __restrict__ ep_off, int* __restrict__ cnt_all,
                             int* __restrict__ ee_csr, int* __restrict__ pe_csr,
                             int* __restrict__ ep_csr){
    int r = blockIdx.x & 7;
    int i = (blockIdx.x >> 3)*256 + threadIdx.x;
    int d, base, n;
    const int* srcp; const int* offp; int* csrp;
    if (i < NEE){ d = __builtin_nontemporal_load(&ee_dst[i]); base = 0; n = NE_N; srcp = ee_src; offp = ee_off; csrp = ee_csr; }
    else if (i < NEE+NPE){ i -= NEE; d = __builtin_nontemporal_load(&pe_dst[i]); base = 100000; n = NE_N; srcp = pe_src; offp = pe_off; csrp = pe_csr; }
    else if (i < ETOT){ i -= NEE+NPE; d = __builtin_nontemporal_load(&ep_dst[i]); base = 200000; n = NPER_N; srcp = ep_src; offp = ep_off; csrp = ep_csr; }
    else return;
    int seg = n >> 3;
    if (d >= r*seg && d < (r+1)*seg){
        int old = atomicAdd(&cnt_all[base + d], -1);
        csrp[offp[d] + old - 1] = __builtin_nontemporal_load(&srcp[i]);
    }
}

// ================= gather aggregation =================
__global__ __launch_bounds__(256)
void agg_emp1(const uint16_t* __restrict__ proj_ee, const uint16_t* __restrict__ proj_pe,
              const int* __restrict__ ee_off, const int* __restrict__ ee_csr,
              const int* __restrict__ pe_off, const int* __restrict__ pe_csr,
              uint16_t* __restrict__ emp1b,
              const float* __restrict__ vvec, float* __restrict__ a_d){
    int w    = (blockIdx.x*blockDim.x + threadIdx.x) >> 6;
    int lane = threadIdx.x & 63;
    if (w >= NE_N) return;
    int grp = lane >> 4, l16 = lane & 15;

    float a[8] = {0,0,0,0,0,0,0,0};
    int b = ee_off[w], e = ee_off[w+1];
    int dee = e - b;
    for (int cb=b; cb<e; cb+=64){
        int j = cb + lane;
        int s = (j<e) ? ee_csr[j] : -1;
        int lim = e - cb; if (lim > 64) lim = 64;
        int iters = (lim + 3) >> 2;
        for (int k=0;k<iters;k++){
            int sg = __shfl(s, k*4 + grp, 64);
            if (sg >= 0){
                uint4 u = *reinterpret_cast<const uint4*>(&proj_ee[(size_t)sg*128 + l16*8]);
                a[0]+=b2f(u.x&0xffffu); a[1]+=b2f(u.x>>16);
                a[2]+=b2f(u.y&0xffffu); a[3]+=b2f(u.y>>16);
                a[4]+=b2f(u.z&0xffffu); a[5]+=b2f(u.z>>16);
                a[6]+=b2f(u.w&0xffffu); a[7]+=b2f(u.w>>16);
            }
        }
    }
    float c[8] = {0,0,0,0,0,0,0,0};
    b = pe_off[w]; e = pe_off[w+1];
    int dpe = e - b;
    for (int cb=b; cb<e; cb+=64){
        int j = cb + lane;
        int s = (j<e) ? pe_csr[j] : -1;
        int lim = e - cb; if (lim > 64) lim = 64;
        int iters = (lim + 3) >> 2;
        for (int k=0;k<iters;k++){
            int sg = __shfl(s, k*4 + grp, 64);
            if (sg >= 0){
                uint4 u = *reinterpret_cast<const uint4*>(&proj_pe[(size_t)sg*128 + l16*8]);
                c[0]+=b2f(u.x&0xffffu); c[1]+=b2f(u.x>>16);
                c[2]+=b2f(u.y&0xffffu); c[3]+=b2f(u.y>>16);
                c[4]+=b2f(u.z&0xffffu); c[5]+=b2f(u.z>>16);
                c[6]+=b2f(u.w&0xffffu); c[7]+=b2f(u.w>>16);
            }
        }
    }
#pragma unroll
    for (int f=0;f<8;f++){
        a[f] += __shfl_xor(a[f],16,64); a[f] += __shfl_xor(a[f],32,64);
        c[f] += __shfl_xor(c[f],16,64); c[f] += __shfl_xor(c[f],32,64);
    }
    if (grp == 0){
        float s1f = 1.f/fmaxf((float)dee,1.f);
        float s2f = 1.f/fmaxf((float)dpe,1.f);
        uint4 sb = *reinterpret_cast<const uint4*>(&emp1b[(size_t)w*128 + l16*8]);
        float sf[8] = { b2f(sb.x&0xffffu), b2f(sb.x>>16), b2f(sb.y&0xffffu), b2f(sb.y>>16),
                        b2f(sb.z&0xffffu), b2f(sb.z>>16), b2f(sb.w&0xffffu), b2f(sb.w>>16) };
        float o[8];
        float partial = 0.f;
        uint32_t ob[8];
#pragma unroll
        for (int f=0;f<8;f++){
            o[f] = fmaxf(sf[f] + a[f]*s1f + c[f]*s2f, 0.f);
            partial += o[f]*vvec[l16*8 + f];
            ob[f] = (uint32_t)f2b(o[f]);
        }
        uint4 pk;
        pk.x = ob[0] | (ob[1]<<16); pk.y = ob[2] | (ob[3]<<16);
        pk.z = ob[4] | (ob[5]<<16); pk.w = ob[6] | (ob[7]<<16);
        *reinterpret_cast<uint4*>(&emp1b[(size_t)w*128 + l16*8]) = pk;
        // a_d[w] = final emp1 row (fp32) @ vvec : reduce across 16 lanes
        partial += __shfl_xor(partial,1,64);
        partial += __shfl_xor(partial,2,64);
        partial += __shfl_xor(partial,4,64);
        partial += __shfl_xor(partial,8,64);
        if (l16 == 0) a_d[w] = partial;
    }
}
__global__ __launch_bounds__(256)
void agg_per1(const uint16_t* __restrict__ proj_ep,
              const int* __restrict__ ep_off, const int* __restrict__ ep_csr,
              uint16_t* __restrict__ per1b){
    int w    = (blockIdx.x*blockDim.x + threadIdx.x) >> 6;
    int lane = threadIdx.x & 63;
    if (w >= NPER_N) return;
    int grp = lane >> 4, l16 = lane & 15;

    float a[8] = {0,0,0,0,0,0,0,0};
    int b = ep_off[w], e = ep_off[w+1];
    int deg = e - b;
    for (int cb=b; cb<e; cb+=64){
        int j = cb + lane;
        int s = (j<e) ? ep_csr[j] : -1;
        int lim = e - cb; if (lim > 64) lim = 64;
        int iters = (lim + 3) >> 2;
        for (int k=0;k<iters;k++){
            int sg = __shfl(s, k*4 + grp, 64);
            if (sg >= 0){
                uint4 u = *reinterpret_cast<const uint4*>(&proj_ep[(size_t)sg*128 + l16*8]);
                a[0]+=b2f(u.x&0xffffu); a[1]+=b2f(u.x>>16);
                a[2]+=b2f(u.y&0xffffu); a[3]+=b2f(u.y>>16);
                a[4]+=b2f(u.z&0xffffu); a[5]+=b2f(u.z>>16);
                a[6]+=b2f(u.w&0xffffu); a[7]+=b2f(u.w>>16);
            }
        }
    }
#pragma unroll
    for (int f=0;f<8;f++){
        a[f] += __shfl_xor(a[f],16,64); a[f] += __shfl_xor(a[f],32,64);
    }
    if (grp == 0){
        float s1f = 1.f/fmaxf((float)deg,1.f);
        uint4 sb = *reinterpret_cast<const uint4*>(&per1b[(size_t)w*128 + l16*8]);
        float sf[8] = { b2f(sb.x&0xffffu), b2f(sb.x>>16), b2f(sb.y&0xffffu), b2f(sb.y>>16),
                        b2f(sb.z&0xffffu), b2f(sb.z>>16), b2f(sb.w&0xffffu), b2f(sb.w>>16) };
        uint32_t o[8];
#pragma unroll
        for (int f=0;f<8;f++) o[f] = (uint32_t)f2b(fmaxf(sf[f] + a[f]*s1f, 0.f));
        uint4 pk;
        pk.x = o[0] | (o[1]<<16); pk.y = o[2] | (o[3]<<16);
        pk.z = o[4] | (o[5]<<16); pk.w = o[6] | (o[7]<<16);
        *reinterpret_cast<uint4*>(&per1b[(size_t)w*128 + l16*8]) = pk;
    }
}
__global__ __launch_bounds__(256)
void agg_per2(const uint16_t* __restrict__ p2ep,
              const int* __restrict__ ep_off, const int* __restrict__ ep_csr,
              float* __restrict__ out){
    int w    = (blockIdx.x*blockDim.x + threadIdx.x) >> 6;
    int lane = threadIdx.x & 63;
    if (w >= NPER_N) return;
    int grp = lane >> 4, l16 = lane & 15;

    float a[4] = {0,0,0,0};
    int b = ep_off[w], e = ep_off[w+1];
    int deg = e - b;
    for (int cb=b; cb<e; cb+=64){
        int j = cb + lane;
        int s = (j<e) ? ep_csr[j] : -1;
        int lim = e - cb; if (lim > 64) lim = 64;
        int iters = (lim + 3) >> 2;
        for (int k=0;k<iters;k++){
            int sg = __shfl(s, k*4 + grp, 64);
            if (sg >= 0){
                uint2 u = *reinterpret_cast<const uint2*>(&p2ep[(size_t)sg*64 + l16*4]);
                a[0]+=b2f(u.x&0xffffu); a[1]+=b2f(u.x>>16);
                a[2]+=b2f(u.y&0xffffu); a[3]+=b2f(u.y>>16);
            }
        }
    }
#pragma unroll
    for (int f=0;f<4;f++){
        a[f] += __shfl_xor(a[f],16,64); a[f] += __shfl_xor(a[f],32,64);
    }
    if (grp == 0){
        float s1f = 1.f/fmaxf((float)deg,1.f);
        float4 o4 = ld4(&out[(size_t)w*64 + l16*4]);
        o4.x += a[0]*s1f; o4.y += a[1]*s1f; o4.z += a[2]*s1f; o4.w += a[3]*s1f;
        st4(&out[(size_t)w*64 + l16*4], o4);
    }
}
// GAT (no max pass: softmax shift-invariant, |logit| small) + SAGE pe mean
__global__ __launch_bounds__(256)
void gat_sage_emp2(const int* __restrict__ ee_off, const int* __restrict__ ee_csr,
                   const int* __restrict__ pe_off, const int* __restrict__ pe_csr,
                   const float* __restrict__ as, const float* __restrict__ ad,
                   const uint16_t* __restrict__ zs, const uint16_t* __restrict__ p2pe,
                   float* __restrict__ out){
    int w    = (blockIdx.x*blockDim.x + threadIdx.x) >> 6;
    int lane = threadIdx.x & 63;
    if (w >= NE_N) return;
    int grp = lane >> 4, l16 = lane & 15;

    float g[4] = {0,0,0,0};
    float invden = 0.f;
    int b = ee_off[w], e = ee_off[w+1];
    if (e > b){
        float add = ad[w];
        float den = 0.f;
        for (int cb=b; cb<e; cb+=64){
            int j = cb + lane;
            int s = 0; float ex = 0.f;
            if (j < e){
                s = ee_csr[j];
                float ev = as[s] + add;
                ev = ev > 0.f ? ev : 0.2f*ev;
                ex = expf(ev);
            }
            den += ex;
            int lim = e - cb; if (lim > 64) lim = 64;
            int iters = (lim + 3) >> 2;
            for (int k=0;k<iters;k++){
                int   sg = __shfl(s,  k*4 + grp, 64);
                float ag = __shfl(ex, k*4 + grp, 64);
                uint2 u = *reinterpret_cast<const uint2*>(&zs[(size_t)sg*64 + l16*4]);
                g[0] += ag*b2f(u.x&0xffffu); g[1] += ag*b2f(u.x>>16);
                g[2] += ag*b2f(u.y&0xffffu); g[3] += ag*b2f(u.y>>16);
            }
        }
        for (int o=32;o;o>>=1) den += __shfl_xor(den,o,64);
        invden = 1.f/den;
    }

    float p[4] = {0,0,0,0};
    b = pe_off[w]; e = pe_off[w+1];
    int deg = e - b;
    for (int cb=b; cb<e; cb+=64){
        int j = cb + lane;
        int s = (j<e) ? pe_csr[j] : -1;
        int lim = e - cb; if (lim > 64) lim = 64;
        int iters = (lim + 3) >> 2;
        for (int k=0;k<iters;k++){
            int sg = __shfl(s, k*4 + grp, 64);
            if (sg >= 0){
                uint2 u = *reinterpret_cast<const uint2*>(&p2pe[(size_t)sg*64 + l16*4]);
                p[0]+=b2f(u.x&0xffffu); p[1]+=b2f(u.x>>16);
                p[2]+=b2f(u.y&0xffffu); p[3]+=b2f(u.y>>16);
            }
        }
    }
#pragma unroll
    for (int f=0;f<4;f++){
        g[f] += __shfl_xor(g[f],16,64); g[f] += __shfl_xor(g[f],32,64);
        p[f] += __shfl_xor(p[f],16,64); p[f] += __shfl_xor(p[f],32,64);
    }
    if (grp == 0){
        float s2f = 1.f/fmaxf((float)deg,1.f);
        float4 o4 = ld4(&out[(size_t)w*64 + l16*4]);
        o4.x += g[0]*invden + p[0]*s2f;
        o4.y += g[1]*invden + p[1]*s2f;
        o4.z += g[2]*invden + p[2]*s2f;
        o4.w += g[3]*invden + p[3]*s2f;
        st4(&out[(size_t)w*64 + l16*4], o4);
    }
}

// ================= prep =================
constexpr int WB_WSUM   = 0;
constexpr int WB_EEWL   = 16384;
constexpr int WB_EPWL   = 32768;
constexpr int WB_PEWL   = 49152;
constexpr int WB_EPWR1  = 65536;
constexpr int WB_LINE   = 81920;
constexpr int WB_LINP   = 90112;
constexpr int WB_GATW   = 94208;
constexpr int WB_S2EPWL = 102400;
constexpr int WB_S2PEWR = 110592;
constexpr int WB_S2PEWL = 118784;
constexpr int WB_S2EPWR = 126976;

__global__ void prep(const float* Wr_ee, const float* Wr_pe,
                     const float* ee_Wl, const float* ep_Wl, const float* pe_Wl, const float* ep_Wr,
                     const float* line_w, const float* linp_w,
                     const float* gatW, const float* s2epWl, const float* s2peWr,
                     const float* s2peWl, const float* s2epWr,
                     const float* bl_ee, const float* bl_pe,
                     const float* s2_pe_bl, const float* gat_b,
                     const float* Wdst, const float* adst,
                     uint16_t* wb, float* bsum1, float* b2sum, float* vvec)
{
    int j = blockIdx.x, t = threadIdx.x;
    if (j == 12){
        if (t < HD){
            bsum1[t] = bl_ee[t] + bl_pe[t];
            float s = 0.f;
            for (int c=0;c<OUTD;c++) s += Wdst[t*OUTD + c]*adst[c];
            vvec[t] = s;
        }
        if (t < OUTD) b2sum[t] = s2_pe_bl[t] + gat_b[t];
        return;
    }
    if (j == 0){
        for (int i=t; i<16384; i+=256) wb[WB_WSUM + i] = f2b(Wr_ee[i] + Wr_pe[i]);
        return;
    }
    const float* src; uint16_t* dst; int n;
    switch(j){
        case 1:  src=ee_Wl;  dst=wb+WB_EEWL;   n=16384; break;
        case 2:  src=ep_Wl;  dst=wb+WB_EPWL;   n=16384; break;
        case 3:  src=pe_Wl;  dst=wb+WB_PEWL;   n=16384; break;
        case 4:  src=ep_Wr;  dst=wb+WB_EPWR1;  n=16384; break;
        case 5:  src=line_w; dst=wb+WB_LINE;   n=8192;  break;
        case 6:  src=linp_w; dst=wb+WB_LINP;   n=4096;  break;
        case 7:  src=gatW;   dst=wb+WB_GATW;   n=8192;  break;
        case 8:  src=s2epWl; dst=wb+WB_S2EPWL; n=8192;  break;
        case 9:  src=s2peWr; dst=wb+WB_S2PEWR; n=8192;  break;
        case 10: src=s2peWl; dst=wb+WB_S2PEWL; n=8192;  break;
        default: src=s2epWr; dst=wb+WB_S2EPWR; n=8192;  break;
    }
    for (int i=t; i<n; i+=256) dst[i] = f2b(src[i]);
}

__global__ void convx(const float* __restrict__ xe, const float* __restrict__ xp,
                      uint16_t* __restrict__ be, uint16_t* __restrict__ bp){
    const int NE4 = NE_N*64/4, NP4 = NPER_N*32/4;
    int i = blockIdx.x*blockDim.x + threadIdx.x;
    if (i < NE4){
        v4fl v = __builtin_nontemporal_load(reinterpret_cast<const v4fl*>(xe + (size_t)i*4));
        uint2 o;
        o.x = (uint32_t)f2b(v.x) | ((uint32_t)f2b(v.y) << 16);
        o.y = (uint32_t)f2b(v.z) | ((uint32_t)f2b(v.w) << 16);
        *reinterpret_cast<uint2*>(&be[(size_t)i*4]) = o;
    } else if (i < NE4 + NP4){
        int k = i - NE4;
        v4fl v = __builtin_nontemporal_load(reinterpret_cast<const v4fl*>(xp + (size_t)k*4));
        uint2 o;
        o.x = (uint32_t)f2b(v.x) | ((uint32_t)f2b(v.y) << 16);
        o.y = (uint32_t)f2b(v.z) | ((uint32_t)f2b(v.w) << 16);
        *reinterpret_cast<uint2*>(&bp[(size_t)k*4]) = o;
    }
}

// ---------------- workspace layout (4B units) ----------------
constexpr size_t OFF_R0 = 0;          // xbe -> zsB
constexpr size_t OFF_R1 = 3200000;    // xbp -> p2peB
constexpr size_t OFF_R2 = 4800000;    // h_empB
constexpr size_t OFF_R3 = 11200000;   // h_perB
constexpr size_t OFF_R4 = 14400000;   // emp1B (6.4M) + per1B (@+6.4M, 3.2M)
constexpr size_t OFF_R5 = 27200000;   // p2epB (3.2M)
constexpr size_t OFF_R6 = 33600000;   // proj_eeB
constexpr size_t OFF_R7 = 40000000;   // proj_peB
constexpr size_t OFF_R8 = 43200000;   // proj_epB
constexpr size_t OFF_AS = 49600000;
constexpr size_t OFF_AD = 49700000;
constexpr size_t OFF_WB = 49800000;
constexpr size_t OFF_BS1= 49900000;
constexpr size_t OFF_BS2= 49900128;
constexpr size_t OFF_VV = 49900192;
constexpr size_t OFF_CNT    = 50000000;
constexpr size_t OFF_EE_OFF = 50250000;
constexpr size_t OFF_PE_OFF = 50350008;
constexpr size_t OFF_EP_OFF = 50450016;
constexpr size_t OFF_PART   = 50500024;
constexpr size_t OFF_EE_CSR = 50500416;
constexpr size_t OFF_PE_CSR = 52100416;
constexpr size_t OFF_EP_CSR = 52900416;

extern "C" void kernel_launch(void* const* d_in, const int* in_sizes, int n_in,
                              void* d_out, int out_size, void* d_ws, size_t ws_size,
                              hipStream_t stream)
{
    const float* x_emp = (const float*)d_in[0];
    const float* x_per = (const float*)d_in[1];
    const int* ee_src = (const int*)d_in[2];
    const int* ee_dst = (const int*)d_in[3];
    const int* pe_src = (const int*)d_in[4];
    const int* pe_dst = (const int*)d_in[5];
    const int* ep_src = (const int*)d_in[6];
    const int* ep_dst = (const int*)d_in[7];
    const float* lin_emp_w=(const float*)d_in[8],  *lin_emp_b=(const float*)d_in[9];
    const float* lin_per_w=(const float*)d_in[10], *lin_per_b=(const float*)d_in[11];
    const float* s1_ee_Wl=(const float*)d_in[12], *s1_ee_bl=(const float*)d_in[13], *s1_ee_Wr=(const float*)d_in[14];
    const float* s1_pe_Wl=(const float*)d_in[15], *s1_pe_bl=(const float*)d_in[16], *s1_pe_Wr=(const float*)d_in[17];
    const float* s1_ep_Wl=(const float*)d_in[18], *s1_ep_bl=(const float*)d_in[19], *s1_ep_Wr=(const float*)d_in[20];
    const float* gat_Wsrc=(const float*)d_in[21], *gat_Wdst=(const float*)d_in[22];
    const float* gat_asrc=(const float*)d_in[23], *gat_adst=(const float*)d_in[24], *gat_b=(const float*)d_in[25];
    const float* s2_pe_Wl=(const float*)d_in[26], *s2_pe_bl=(const float*)d_in[27], *s2_pe_Wr=(const float*)d_in[28];
    const float* s2_ep_Wl=(const float*)d_in[29], *s2_ep_bl=(const float*)d_in[30], *s2_ep_Wr=(const float*)d_in[31];

    float* ws = (float*)d_ws;
    int*   wi = (int*)d_ws;
    float* out_emp = (float*)d_out;
    float* out_per = out_emp + (size_t)NE_N*OUTD;

    uint16_t* xbe     = (uint16_t*)(ws + OFF_R0);
    uint16_t* zsB     = (uint16_t*)(ws + OFF_R0);
    uint16_t* xbp     = (uint16_t*)(ws + OFF_R1);
    uint16_t* p2peB   = (uint16_t*)(ws + OFF_R1);
    uint16_t* h_empB  = (uint16_t*)(ws + OFF_R2);
    uint16_t* h_perB  = (uint16_t*)(ws + OFF_R3);
    uint16_t* emp1B   = (uint16_t*)(ws + OFF_R4);
    uint16_t* per1B   = (uint16_t*)(ws + OFF_R4 + 6400000);
    uint16_t* p2epB   = (uint16_t*)(ws + OFF_R5);
    uint16_t* proj_eeB= (uint16_t*)(ws + OFF_R6);
    uint16_t* proj_peB= (uint16_t*)(ws + OFF_R7);
    uint16_t* proj_epB= (uint16_t*)(ws + OFF_R8);
    float* a_s   = ws + OFF_AS;
    float* a_d   = ws + OFF_AD;
    uint16_t* WB = (uint16_t*)(ws + OFF_WB);
    float* bsum1 = ws + OFF_BS1;
    float* b2sum = ws + OFF_BS2;
    float* vvec  = ws + OFF_VV;

    int* cnt_all = wi + OFF_CNT;
    int* ee_off = wi + OFF_EE_OFF; int* ee_csr = wi + OFF_EE_CSR;
    int* pe_off = wi + OFF_PE_OFF; int* pe_csr = wi + OFF_PE_CSR;
    int* ep_off = wi + OFF_EP_OFF; int* ep_csr = wi + OFF_EP_CSR;
    int* part   = wi + OFF_PART;

    const int GE = ceil_div(NE_N,256), GP = ceil_div(NPER_N,256);

    hipMemsetAsync(cnt_all, 0, 250000*sizeof(int), stream);

    prep<<<13,256,0,stream>>>(s1_ee_Wr, s1_pe_Wr, s1_ee_Wl, s1_ep_Wl, s1_pe_Wl, s1_ep_Wr,
                              lin_emp_w, lin_per_w,
                              gat_Wsrc, s2_ep_Wl, s2_pe_Wr, s2_pe_Wl, s2_ep_Wr,
                              s1_ee_bl, s1_pe_bl, s2_pe_bl, gat_b, gat_Wdst, gat_adst,
                              WB, bsum1, b2sum, vvec);
    convx<<<ceil_div(NE_N*64/4 + NPER_N*32/4, 256),256,0,stream>>>(x_emp, x_per, xbe, xbp);

    // ---- CSR build ----
    count_all<<<ceil_div(ETOT,256),256,0,stream>>>(ee_dst, pe_dst, ep_dst, cnt_all);
    scan_block3<<<dim3(ceil_div(NE_N,1024),3),256,0,stream>>>(cnt_all, ee_off, pe_off, ep_off, part);
    scan_partial3<<<3,64,0,stream>>>(part);
    add_base3<<<ceil_div(2*(NE_N+1)+NPER_N+1,256),256,0,stream>>>(ee_off, pe_off, ep_off, part);
    const int NCHUNK = ceil_div(ETOT,256);
    fill_sharded<<<NCHUNK*8,256,0,stream>>>(ee_src, ee_dst, pe_src, pe_dst, ep_src, ep_dst,
                                            ee_off, pe_off, ep_off, cnt_all,
                                            ee_csr, pe_csr, ep_csr);

    // ---- GEMMs ----
    {
        Segs g{};
        g.s[0] = Seg{WB+WB_LINE,    lin_emp_b,    (void*)h_empB,      nullptr,nullptr, 128,128,2};
        g.s[1] = Seg{WB+WB_LINE+64, lin_emp_b+64, (void*)(h_empB+64), nullptr,nullptr, 128,128,2};
        g.s[2]=g.s[0]; g.s[3]=g.s[0]; g.s[4]=g.s[0]; g.s[5]=g.s[0];
        gemm_mfma<64><<<dim3(GE,2),256,0,stream>>>(xbe, NE_N, g);
    }
    {
        Segs g{};
        g.s[0] = Seg{WB+WB_LINP,    lin_per_b,    (void*)h_perB,      nullptr,nullptr, 128,128,2};
        g.s[1] = Seg{WB+WB_LINP+64, lin_per_b+64, (void*)(h_perB+64), nullptr,nullptr, 128,128,2};
        g.s[2]=g.s[0]; g.s[3]=g.s[0]; g.s[4]=g.s[0]; g.s[5]=g.s[0];
        gemm_mfma<32><<<dim3(GP,2),256,0,stream>>>(xbp, NPER_N, g);
    }
    {   // conv1 from h_emp: emp1 base (bf16+bias), proj_ee, proj_ep
        Segs g{};
        g.s[0] = Seg{WB+WB_WSUM,    bsum1,    (void*)emp1B,        nullptr,nullptr, 128,128,3};
        g.s[1] = Seg{WB+WB_WSUM+64, bsum1+64, (void*)(emp1B+64),   nullptr,nullptr, 128,128,3};
        g.s[2] = Seg{WB+WB_EEWL,    nullptr,  (void*)proj_eeB,     nullptr,nullptr, 128,128,1};
        g.s[3] = Seg{WB+WB_EEWL+64, nullptr,  (void*)(proj_eeB+64),nullptr,nullptr, 128,128,1};
        g.s[4] = Seg{WB+WB_EPWL,    nullptr,  (void*)proj_epB,     nullptr,nullptr, 128,128,1};
        g.s[5] = Seg{WB+WB_EPWL+64, nullptr,  (void*)(proj_epB+64),nullptr,nullptr, 128,128,1};
        gemm_mfma<128><<<dim3(GE,6),256,0,stream>>>(h_empB, NE_N, g);
    }
    {   // conv1 from h_per: proj_pe, per1 base (bf16+bias)
        Segs g{};
        g.s[0] = Seg{WB+WB_PEWL,    nullptr,     (void*)proj_peB,     nullptr,nullptr, 128,128,1};
        g.s[1] = Seg{WB+WB_PEWL+64, nullptr,     (void*)(proj_peB+64),nullptr,nullptr, 128,128,1};
        g.s[2] = Seg{WB+WB_EPWR1,   s1_ep_bl,    (void*)per1B,        nullptr,nullptr, 128,128,3};
        g.s[3] = Seg{WB+WB_EPWR1+64,s1_ep_bl+64, (void*)(per1B+64),   nullptr,nullptr, 128,128,3};
        g.s[4]=g.s[0]; g.s[5]=g.s[0];
        gemm_mfma<128><<<dim3(GP,4),256,0,stream>>>(h_perB, NPER_N, g);
    }
    agg_emp1<<<ceil_div((long long)NE_N*64,256),256,0,stream>>>(proj_eeB, proj_peB, ee_off, ee_csr, pe_off, pe_csr, emp1B, vvec, a_d);
    agg_per1<<<ceil_div((long long)NPER_N*64,256),256,0,stream>>>(proj_epB, ep_off, ep_csr, per1B);

    {   // conv2 from emp1: zs (+fused a_s), p2ep, emp2 base
        Segs g{};
        g.s[0] = Seg{WB+WB_GATW,   nullptr, (void*)zsB,     gat_asrc, a_s,  64,64,4};
        g.s[1] = Seg{WB+WB_S2EPWL, nullptr, (void*)p2epB,   nullptr, nullptr, 64,64,1};
        g.s[2] = Seg{WB+WB_S2PEWR, b2sum,   (void*)out_emp, nullptr, nullptr, 64,64,0};
        g.s[3]=g.s[1]; g.s[4]=g.s[1]; g.s[5]=g.s[1];
        gemm_mfma<128><<<dim3(GE,3),256,0,stream>>>(emp1B, NE_N, g);
    }
    {   // conv2 from per1
        Segs g{};
        g.s[0] = Seg{WB+WB_S2PEWL, nullptr,  (void*)p2peB,   nullptr,nullptr, 64,64,1};
        g.s[1] = Seg{WB+WB_S2EPWR, s2_ep_bl, (void*)out_per, nullptr,nullptr, 64,64,0};
        g.s[2]=g.s[0]; g.s[3]=g.s[0]; g.s[4]=g.s[0]; g.s[5]=g.s[0];
        gemm_mfma<128><<<dim3(GP,2),256,0,stream>>>(per1B, NPER_N, g);
    }

    gat_sage_emp2<<<ceil_div((long long)NE_N*64,256),256,0,stream>>>(ee_off, ee_csr, pe_off, pe_csr, a_s, a_d, zsB, p2peB, out_emp);
    agg_per2<<<ceil_div((long long)NPER_N*64,256),256,0,stream>>>(p2epB, ep_off, ep_csr, out_per);
}

// Round 15
// 735.745 us; speedup vs baseline: 1.4725x; 1.0154x over previous
//
#include <hip/hip_runtime.h>
#include <cstdint>

#define NE_N   100000
#define NPER_N 50000
#define HD     128
#define OUTD   64
#define NEE    1600000
#define NPE    800000
#define NEP    800000
#define ETOT   (NEE+NPE+NEP)

static inline int ceil_div(long long a, long long b){ return (int)((a + b - 1)/b); }

__device__ __forceinline__ float4 ld4(const float* p){ return *reinterpret_cast<const float4*>(p); }
__device__ __forceinline__ void st4(float* p, float4 v){ *reinterpret_cast<float4*>(p) = v; }
__device__ __forceinline__ uint16_t f2b(float f){            // fp32 -> bf16 RNE
    uint32_t u = __float_as_uint(f);
    u += 0x7fffu + ((u >> 16) & 1u);
    return (uint16_t)(u >> 16);
}
__device__ __forceinline__ float b2f(uint32_t u){ return __uint_as_float(u << 16); }

typedef short v8s __attribute__((ext_vector_type(8)));
typedef float v4f __attribute__((ext_vector_type(4)));
typedef float v4fl __attribute__((ext_vector_type(4)));   // nt-loadable float4

// ================= MFMA bf16 GEMM =================
// mode: 0 = f32 out + bias ; 1 = bf16 out ; 2 = bf16 + bias + relu ; 3 = bf16 + bias
//       4 = bf16 out + fused row-dot with aux -> auxout  (a_s = zs @ asrc)
struct Seg { const uint16_t* W; const float* b; void* C;
             const float* aux; float* auxout; int ldw; int ldc; int mode; };
struct Segs { Seg s[6]; };

template<int K>
__global__ __launch_bounds__(256)
void gemm_mfma(const uint16_t* __restrict__ A, int N, Segs segs)
{
    constexpr int NKS  = K / 32;
    constexpr int PADK = K + 8;
    __shared__ __align__(16) uint16_t Wt[64 * PADK];

    Seg sg = segs.s[blockIdx.y];

    const int t = threadIdx.x;
    for (int i = t; i < K*64; i += 256){
        int k = i >> 6, c = i & 63;
        Wt[c*PADK + k] = sg.W[(size_t)k*sg.ldw + c];
    }
    __syncthreads();

    const int lane = t & 63, wid = t >> 6;
    const int l16 = lane & 15, lg = lane >> 4;
    const int rowbase = blockIdx.x*256 + wid*64;

    v4f acc[4][4];
#pragma unroll
    for (int i=0;i<4;i++)
#pragma unroll
        for (int j=0;j<4;j++) acc[i][j] = (v4f){0.f,0.f,0.f,0.f};

#pragma unroll
    for (int ks=0; ks<NKS; ks++){
        const int koff = ks*32 + lg*8;
        v8s a[4], b[4];
#pragma unroll
        for (int rt=0;rt<4;rt++){
            int r = rowbase + rt*16 + l16; if (r > N-1) r = N-1;
            a[rt] = *reinterpret_cast<const v8s*>(&A[(size_t)r*K + koff]);
        }
#pragma unroll
        for (int ct=0;ct<4;ct++)
            b[ct] = *reinterpret_cast<const v8s*>(&Wt[(ct*16 + l16)*PADK + koff]);
#pragma unroll
        for (int rt=0;rt<4;rt++)
#pragma unroll
            for (int ct=0;ct<4;ct++)
                acc[rt][ct] = __builtin_amdgcn_mfma_f32_16x16x32_bf16(a[rt], b[ct], acc[rt][ct], 0, 0, 0);
    }

    const int mode = sg.mode, ldc = sg.ldc;
    float bias[4];
    if (mode == 0 || mode == 2 || mode == 3){
#pragma unroll
        for (int ct=0;ct<4;ct++) bias[ct] = sg.b[ct*16 + l16];
    }
    float aux[4];
    if (mode == 4){
#pragma unroll
        for (int ct=0;ct<4;ct++) aux[ct] = sg.aux[ct*16 + l16];
    }
#pragma unroll
    for (int rt=0;rt<4;rt++){
#pragma unroll
        for (int rg=0;rg<4;rg++){
            int r = rowbase + rt*16 + lg*4 + rg;
            bool valid = (r < N);
            float partial = 0.f;
            if (valid){
#pragma unroll
                for (int ct=0;ct<4;ct++){
                    float v = acc[rt][ct][rg];
                    int c = ct*16 + l16;
                    if (mode == 0)
                        ((float*)sg.C)[(size_t)r*ldc + c] = v + bias[ct];
                    else if (mode == 1)
                        ((uint16_t*)sg.C)[(size_t)r*ldc + c] = f2b(v);
                    else if (mode == 2)
                        ((uint16_t*)sg.C)[(size_t)r*ldc + c] = f2b(fmaxf(v + bias[ct], 0.f));
                    else if (mode == 3)
                        ((uint16_t*)sg.C)[(size_t)r*ldc + c] = f2b(v + bias[ct]);
                    else {
                        ((uint16_t*)sg.C)[(size_t)r*ldc + c] = f2b(v);
                        partial += v*aux[ct];
                    }
                }
            }
            if (mode == 4){
                partial += __shfl_xor(partial,1,64);
                partial += __shfl_xor(partial,2,64);
                partial += __shfl_xor(partial,4,64);
                partial += __shfl_xor(partial,8,64);
                if (valid && l16 == 0) sg.auxout[r] = partial;
            }
        }
    }
}

// ================= CSR build =================
__global__ void count_all(const int* __restrict__ ee, const int* __restrict__ pe,
                          const int* __restrict__ ep, int* __restrict__ cnt){
    int i = blockIdx.x*blockDim.x + threadIdx.x;
    if (i < NEE) atomicAdd(&cnt[__builtin_nontemporal_load(&ee[i])], 1);
    else if (i < NEE+NPE) atomicAdd(&cnt[100000 + __builtin_nontemporal_load(&pe[i-NEE])], 1);
    else if (i < ETOT) atomicAdd(&cnt[200000 + __builtin_nontemporal_load(&ep[i-NEE-NPE])], 1);
}
__global__ __launch_bounds__(256)
void scan_block3(const int* __restrict__ cnt_all, int* __restrict__ ee_off,
                 int* __restrict__ pe_off, int* __restrict__ ep_off,
                 int* __restrict__ partial){
    int r = blockIdx.y;
    const int* cnt = cnt_all + (r==0 ? 0 : (r==1 ? 100000 : 200000));
    int* off = (r==0) ? ee_off : (r==1 ? pe_off : ep_off);
    int n = (r==2) ? NPER_N : NE_N;
    int* part = partial + r*128;

    __shared__ int sh[256];
    int t = threadIdx.x;
    int base = blockIdx.x*1024 + t*4;
    int v0 = (base  <n)?cnt[base  ]:0;
    int v1 = (base+1<n)?cnt[base+1]:0;
    int v2 = (base+2<n)?cnt[base+2]:0;
    int v3 = (base+3<n)?cnt[base+3]:0;
    int tsum = v0+v1+v2+v3;
    sh[t]=tsum; __syncthreads();
    for (int d=1; d<256; d<<=1){
        int x = (t>=d)? sh[t-d] : 0;
        __syncthreads();
        sh[t] += x;
        __syncthreads();
    }
    int ex = sh[t]-tsum;
    if (base  <n) off[base  ]=ex;
    if (base+1<n) off[base+1]=ex+v0;
    if (base+2<n) off[base+2]=ex+v0+v1;
    if (base+3<n) off[base+3]=ex+v0+v1+v2;
    if (t==255) part[blockIdx.x]=sh[255];
}
__global__ void scan_partial3(int* __restrict__ partial){
    int r = blockIdx.x;
    if (threadIdx.x != 0) return;
    int n = (r==2) ? NPER_N : NE_N;
    int nb = (n + 1023) >> 10;
    int* p = partial + r*128;
    int run = 0;
    for (int i=0;i<nb;i++){ int v=p[i]; p[i]=run; run+=v; }
}
__global__ void add_base3(int* __restrict__ ee_off, int* __restrict__ pe_off,
                          int* __restrict__ ep_off, const int* __restrict__ partial){
    int i = blockIdx.x*blockDim.x + threadIdx.x;
    if (i <= NE_N){
        if (i < NE_N) ee_off[i] += partial[i>>10];
        else ee_off[NE_N] = NEE;
    } else if (i <= 2*NE_N + 1){
        int k = i - (NE_N+1);
        if (k < NE_N) pe_off[k] += partial[128 + (k>>10)];
        else pe_off[NE_N] = NPE;
    } else {
        int k = i - 2*(NE_N+1);
        if (k < NPER_N) ep_off[k] += partial[256 + (k>>10)];
        else if (k == NPER_N) ep_off[NPER_N] = NEP;
    }
}
__global__ void fill_sharded(const int* __restrict__ ee_src, const int* __restrict__ ee_dst,
                             const int* __restrict__ pe_src, const int* __restrict__ pe_dst,
                             const int* __restrict__ ep_src, const int* __restrict__ ep_dst,
                             const int* __restrict__ ee_off, const int* __restrict__ pe_off,
                             const int* __restrict__ ep_off, int* __restrict__ cnt_all,
                             int* __restrict__ ee_csr, int* __restrict__ pe_csr,
                             int* __restrict__ ep_csr){
    int r = blockIdx.x & 7;
    int i = (blockIdx.x >> 3)*256 + threadIdx.x;
    int d, base, n;
    const int* srcp; const int* offp; int* csrp;
    if (i < NEE){ d = __builtin_nontemporal_load(&ee_dst[i]); base = 0; n = NE_N; srcp = ee_src; offp = ee_off; csrp = ee_csr; }
    else if (i < NEE+NPE){ i -= NEE; d = __builtin_nontemporal_load(&pe_dst[i]); base = 100000; n = NE_N; srcp = pe_src; offp = pe_off; csrp = pe_csr; }
    else if (i < ETOT){ i -= NEE+NPE; d = __builtin_nontemporal_load(&ep_dst[i]); base = 200000; n = NPER_N; srcp = ep_src; offp = ep_off; csrp = ep_csr; }
    else return;
    int seg = n >> 3;
    if (d >= r*seg && d < (r+1)*seg){
        int old = atomicAdd(&cnt_all[base + d], -1);
        csrp[offp[d] + old - 1] = __builtin_nontemporal_load(&srcp[i]);
    }
}

// ================= gather aggregation =================
// fused conv1: waves [0,NE_N) -> emp1 (+a_d GEMV); [NE_N, NE_N+NPER_N) -> per1
__global__ __launch_bounds__(256)
void agg1_fused(const uint16_t* __restrict__ proj_ee, const uint16_t* __restrict__ proj_pe,
                const uint16_t* __restrict__ proj_ep,
                const int* __restrict__ ee_off, const int* __restrict__ ee_csr,
                const int* __restrict__ pe_off, const int* __restrict__ pe_csr,
                const int* __restrict__ ep_off, const int* __restrict__ ep_csr,
                uint16_t* __restrict__ emp1b, uint16_t* __restrict__ per1b,
                const float* __restrict__ vvec, float* __restrict__ a_d){
    int gw   = (blockIdx.x*blockDim.x + threadIdx.x) >> 6;
    int lane = threadIdx.x & 63;
    int grp = lane >> 4, l16 = lane & 15;

    if (gw < NE_N){
        int w = gw;
        float a[8] = {0,0,0,0,0,0,0,0};
        int b = ee_off[w], e = ee_off[w+1];
        int dee = e - b;
        for (int cb=b; cb<e; cb+=64){
            int j = cb + lane;
            int s = (j<e) ? ee_csr[j] : -1;
            int lim = e - cb; if (lim > 64) lim = 64;
            int iters = (lim + 3) >> 2;
            for (int k=0;k<iters;k++){
                int sg = __shfl(s, k*4 + grp, 64);
                if (sg >= 0){
                    uint4 u = *reinterpret_cast<const uint4*>(&proj_ee[(size_t)sg*128 + l16*8]);
                    a[0]+=b2f(u.x&0xffffu); a[1]+=b2f(u.x>>16);
                    a[2]+=b2f(u.y&0xffffu); a[3]+=b2f(u.y>>16);
                    a[4]+=b2f(u.z&0xffffu); a[5]+=b2f(u.z>>16);
                    a[6]+=b2f(u.w&0xffffu); a[7]+=b2f(u.w>>16);
                }
            }
        }
        float c[8] = {0,0,0,0,0,0,0,0};
        b = pe_off[w]; e = pe_off[w+1];
        int dpe = e - b;
        for (int cb=b; cb<e; cb+=64){
            int j = cb + lane;
            int s = (j<e) ? pe_csr[j] : -1;
            int lim = e - cb; if (lim > 64) lim = 64;
            int iters = (lim + 3) >> 2;
            for (int k=0;k<iters;k++){
                int sg = __shfl(s, k*4 + grp, 64);
                if (sg >= 0){
                    uint4 u = *reinterpret_cast<const uint4*>(&proj_pe[(size_t)sg*128 + l16*8]);
                    c[0]+=b2f(u.x&0xffffu); c[1]+=b2f(u.x>>16);
                    c[2]+=b2f(u.y&0xffffu); c[3]+=b2f(u.y>>16);
                    c[4]+=b2f(u.z&0xffffu); c[5]+=b2f(u.z>>16);
                    c[6]+=b2f(u.w&0xffffu); c[7]+=b2f(u.w>>16);
                }
            }
        }
#pragma unroll
        for (int f=0;f<8;f++){
            a[f] += __shfl_xor(a[f],16,64); a[f] += __shfl_xor(a[f],32,64);
            c[f] += __shfl_xor(c[f],16,64); c[f] += __shfl_xor(c[f],32,64);
        }
        if (grp == 0){
            float s1f = 1.f/fmaxf((float)dee,1.f);
            float s2f = 1.f/fmaxf((float)dpe,1.f);
            uint4 sb = *reinterpret_cast<const uint4*>(&emp1b[(size_t)w*128 + l16*8]);
            float sf[8] = { b2f(sb.x&0xffffu), b2f(sb.x>>16), b2f(sb.y&0xffffu), b2f(sb.y>>16),
                            b2f(sb.z&0xffffu), b2f(sb.z>>16), b2f(sb.w&0xffffu), b2f(sb.w>>16) };
            float o[8];
            float partial = 0.f;
            uint32_t ob[8];
#pragma unroll
            for (int f=0;f<8;f++){
                o[f] = fmaxf(sf[f] + a[f]*s1f + c[f]*s2f, 0.f);
                partial += o[f]*vvec[l16*8 + f];
                ob[f] = (uint32_t)f2b(o[f]);
            }
            uint4 pk;
            pk.x = ob[0] | (ob[1]<<16); pk.y = ob[2] | (ob[3]<<16);
            pk.z = ob[4] | (ob[5]<<16); pk.w = ob[6] | (ob[7]<<16);
            *reinterpret_cast<uint4*>(&emp1b[(size_t)w*128 + l16*8]) = pk;
            partial += __shfl_xor(partial,1,64);
            partial += __shfl_xor(partial,2,64);
            partial += __shfl_xor(partial,4,64);
            partial += __shfl_xor(partial,8,64);
            if (l16 == 0) a_d[w] = partial;
        }
    } else if (gw < NE_N + NPER_N){
        int w = gw - NE_N;
        float a[8] = {0,0,0,0,0,0,0,0};
        int b = ep_off[w], e = ep_off[w+1];
        int deg = e - b;
        for (int cb=b; cb<e; cb+=64){
            int j = cb + lane;
            int s = (j<e) ? ep_csr[j] : -1;
            int lim = e - cb; if (lim > 64) lim = 64;
            int iters = (lim + 3) >> 2;
            for (int k=0;k<iters;k++){
                int sg = __shfl(s, k*4 + grp, 64);
                if (sg >= 0){
                    uint4 u = *reinterpret_cast<const uint4*>(&proj_ep[(size_t)sg*128 + l16*8]);
                    a[0]+=b2f(u.x&0xffffu); a[1]+=b2f(u.x>>16);
                    a[2]+=b2f(u.y&0xffffu); a[3]+=b2f(u.y>>16);
                    a[4]+=b2f(u.z&0xffffu); a[5]+=b2f(u.z>>16);
                    a[6]+=b2f(u.w&0xffffu); a[7]+=b2f(u.w>>16);
                }
            }
        }
#pragma unroll
        for (int f=0;f<8;f++){
            a[f] += __shfl_xor(a[f],16,64); a[f] += __shfl_xor(a[f],32,64);
        }
        if (grp == 0){
            float s1f = 1.f/fmaxf((float)deg,1.f);
            uint4 sb = *reinterpret_cast<const uint4*>(&per1b[(size_t)w*128 + l16*8]);
            float sf[8] = { b2f(sb.x&0xffffu), b2f(sb.x>>16), b2f(sb.y&0xffffu), b2f(sb.y>>16),
                            b2f(sb.z&0xffffu), b2f(sb.z>>16), b2f(sb.w&0xffffu), b2f(sb.w>>16) };
            uint32_t o[8];
#pragma unroll
            for (int f=0;f<8;f++) o[f] = (uint32_t)f2b(fmaxf(sf[f] + a[f]*s1f, 0.f));
            uint4 pk;
            pk.x = o[0] | (o[1]<<16); pk.y = o[2] | (o[3]<<16);
            pk.z = o[4] | (o[5]<<16); pk.w = o[6] | (o[7]<<16);
            *reinterpret_cast<uint4*>(&per1b[(size_t)w*128 + l16*8]) = pk;
        }
    }
}
// fused conv2: waves [0,NE_N) -> GAT(no-max)+SAGE-pe emp2; rest -> per2 ep-mean
__global__ __launch_bounds__(256)
void agg2_fused(const int* __restrict__ ee_off, const int* __restrict__ ee_csr,
                const int* __restrict__ pe_off, const int* __restrict__ pe_csr,
                const int* __restrict__ ep_off, const int* __restrict__ ep_csr,
                const float* __restrict__ as, const float* __restrict__ ad,
                const uint16_t* __restrict__ zs, const uint16_t* __restrict__ p2pe,
                const uint16_t* __restrict__ p2ep,
                float* __restrict__ out_emp, float* __restrict__ out_per){
    int gw   = (blockIdx.x*blockDim.x + threadIdx.x) >> 6;
    int lane = threadIdx.x & 63;
    int grp = lane >> 4, l16 = lane & 15;

    if (gw < NE_N){
        int w = gw;
        float g[4] = {0,0,0,0};
        float invden = 0.f;
        int b = ee_off[w], e = ee_off[w+1];
        if (e > b){
            float add = ad[w];
            float den = 0.f;
            for (int cb=b; cb<e; cb+=64){
                int j = cb + lane;
                int s = 0; float ex = 0.f;
                if (j < e){
                    s = ee_csr[j];
                    float ev = as[s] + add;
                    ev = ev > 0.f ? ev : 0.2f*ev;
                    ex = expf(ev);
                }
                den += ex;
                int lim = e - cb; if (lim > 64) lim = 64;
                int iters = (lim + 3) >> 2;
                for (int k=0;k<iters;k++){
                    int   sg = __shfl(s,  k*4 + grp, 64);
                    float ag = __shfl(ex, k*4 + grp, 64);
                    uint2 u = *reinterpret_cast<const uint2*>(&zs[(size_t)sg*64 + l16*4]);
                    g[0] += ag*b2f(u.x&0xffffu); g[1] += ag*b2f(u.x>>16);
                    g[2] += ag*b2f(u.y&0xffffu); g[3] += ag*b2f(u.y>>16);
                }
            }
            for (int o=32;o;o>>=1) den += __shfl_xor(den,o,64);
            invden = 1.f/den;
        }

        float p[4] = {0,0,0,0};
        b = pe_off[w]; e = pe_off[w+1];
        int deg = e - b;
        for (int cb=b; cb<e; cb+=64){
            int j = cb + lane;
            int s = (j<e) ? pe_csr[j] : -1;
            int lim = e - cb; if (lim > 64) lim = 64;
            int iters = (lim + 3) >> 2;
            for (int k=0;k<iters;k++){
                int sg = __shfl(s, k*4 + grp, 64);
                if (sg >= 0){
                    uint2 u = *reinterpret_cast<const uint2*>(&p2pe[(size_t)sg*64 + l16*4]);
                    p[0]+=b2f(u.x&0xffffu); p[1]+=b2f(u.x>>16);
                    p[2]+=b2f(u.y&0xffffu); p[3]+=b2f(u.y>>16);
                }
            }
        }
#pragma unroll
        for (int f=0;f<4;f++){
            g[f] += __shfl_xor(g[f],16,64); g[f] += __shfl_xor(g[f],32,64);
            p[f] += __shfl_xor(p[f],16,64); p[f] += __shfl_xor(p[f],32,64);
        }
        if (grp == 0){
            float s2f = 1.f/fmaxf((float)deg,1.f);
            float4 o4 = ld4(&out_emp[(size_t)w*64 + l16*4]);
            o4.x += g[0]*invden + p[0]*s2f;
            o4.y += g[1]*invden + p[1]*s2f;
            o4.z += g[2]*invden + p[2]*s2f;
            o4.w += g[3]*invden + p[3]*s2f;
            st4(&out_emp[(size_t)w*64 + l16*4], o4);
        }
    } else if (gw < NE_N + NPER_N){
        int w = gw - NE_N;
        float a[4] = {0,0,0,0};
        int b = ep_off[w], e = ep_off[w+1];
        int deg = e - b;
        for (int cb=b; cb<e; cb+=64){
            int j = cb + lane;
            int s = (j<e) ? ep_csr[j] : -1;
            int lim = e - cb; if (lim > 64) lim = 64;
            int iters = (lim + 3) >> 2;
            for (int k=0;k<iters;k++){
                int sg = __shfl(s, k*4 + grp, 64);
                if (sg >= 0){
                    uint2 u = *reinterpret_cast<const uint2*>(&p2ep[(size_t)sg*64 + l16*4]);
                    a[0]+=b2f(u.x&0xffffu); a[1]+=b2f(u.x>>16);
                    a[2]+=b2f(u.y&0xffffu); a[3]+=b2f(u.y>>16);
                }
            }
        }
#pragma unroll
        for (int f=0;f<4;f++){
            a[f] += __shfl_xor(a[f],16,64); a[f] += __shfl_xor(a[f],32,64);
        }
        if (grp == 0){
            float s1f = 1.f/fmaxf((float)deg,1.f);
            float4 o4 = ld4(&out_per[(size_t)w*64 + l16*4]);
            o4.x += a[0]*s1f; o4.y += a[1]*s1f; o4.z += a[2]*s1f; o4.w += a[3]*s1f;
            st4(&out_per[(size_t)w*64 + l16*4], o4);
        }
    }
}

// ================= prep =================
constexpr int WB_WSUM   = 0;
constexpr int WB_EEWL   = 16384;
constexpr int WB_EPWL   = 32768;
constexpr int WB_PEWL   = 49152;
constexpr int WB_EPWR1  = 65536;
constexpr int WB_LINE   = 81920;
constexpr int WB_LINP   = 90112;
constexpr int WB_GATW   = 94208;
constexpr int WB_S2EPWL = 102400;
constexpr int WB_S2PEWR = 110592;
constexpr int WB_S2PEWL = 118784;
constexpr int WB_S2EPWR = 126976;

__global__ void prep(const float* Wr_ee, const float* Wr_pe,
                     const float* ee_Wl, const float* ep_Wl, const float* pe_Wl, const float* ep_Wr,
                     const float* line_w, const float* linp_w,
                     const float* gatW, const float* s2epWl, const float* s2peWr,
                     const float* s2peWl, const float* s2epWr,
                     const float* bl_ee, const float* bl_pe,
                     const float* s2_pe_bl, const float* gat_b,
                     const float* Wdst, const float* adst,
                     uint16_t* wb, float* bsum1, float* b2sum, float* vvec)
{
    int j = blockIdx.x, t = threadIdx.x;
    if (j == 12){
        if (t < HD){
            bsum1[t] = bl_ee[t] + bl_pe[t];
            float s = 0.f;
            for (int c=0;c<OUTD;c++) s += Wdst[t*OUTD + c]*adst[c];
            vvec[t] = s;
        }
        if (t < OUTD) b2sum[t] = s2_pe_bl[t] + gat_b[t];
        return;
    }
    if (j == 0){
        for (int i=t; i<16384; i+=256) wb[WB_WSUM + i] = f2b(Wr_ee[i] + Wr_pe[i]);
        return;
    }
    const float* src; uint16_t* dst; int n;
    switch(j){
        case 1:  src=ee_Wl;  dst=wb+WB_EEWL;   n=16384; break;
        case 2:  src=ep_Wl;  dst=wb+WB_EPWL;   n=16384; break;
        case 3:  src=pe_Wl;  dst=wb+WB_PEWL;   n=16384; break;
        case 4:  src=ep_Wr;  dst=wb+WB_EPWR1;  n=16384; break;
        case 5:  src=line_w; dst=wb+WB_LINE;   n=8192;  break;
        case 6:  src=linp_w; dst=wb+WB_LINP;   n=4096;  break;
        case 7:  src=gatW;   dst=wb+WB_GATW;   n=8192;  break;
        case 8:  src=s2epWl; dst=wb+WB_S2EPWL; n=8192;  break;
        case 9:  src=s2peWr; dst=wb+WB_S2PEWR; n=8192;  break;
        case 10: src=s2peWl; dst=wb+WB_S2PEWL; n=8192;  break;
        default: src=s2epWr; dst=wb+WB_S2EPWR; n=8192;  break;
    }
    for (int i=t; i<n; i+=256) dst[i] = f2b(src[i]);
}

__global__ void convx(const float* __restrict__ xe, const float* __restrict__ xp,
                      uint16_t* __restrict__ be, uint16_t* __restrict__ bp){
    const int NE4 = NE_N*64/4, NP4 = NPER_N*32/4;
    int i = blockIdx.x*blockDim.x + threadIdx.x;
    if (i < NE4){
        v4fl v = __builtin_nontemporal_load(reinterpret_cast<const v4fl*>(xe + (size_t)i*4));
        uint2 o;
        o.x = (uint32_t)f2b(v.x) | ((uint32_t)f2b(v.y) << 16);
        o.y = (uint32_t)f2b(v.z) | ((uint32_t)f2b(v.w) << 16);
        *reinterpret_cast<uint2*>(&be[(size_t)i*4]) = o;
    } else if (i < NE4 + NP4){
        int k = i - NE4;
        v4fl v = __builtin_nontemporal_load(reinterpret_cast<const v4fl*>(xp + (size_t)k*4));
        uint2 o;
        o.x = (uint32_t)f2b(v.x) | ((uint32_t)f2b(v.y) << 16);
        o.y = (uint32_t)f2b(v.z) | ((uint32_t)f2b(v.w) << 16);
        *reinterpret_cast<uint2*>(&bp[(size_t)k*4]) = o;
    }
}

// ---------------- workspace layout (4B units) ----------------
constexpr size_t OFF_R0 = 0;          // xbe -> zsB
constexpr size_t OFF_R1 = 3200000;    // xbp -> p2peB
constexpr size_t OFF_R2 = 4800000;    // h_empB
constexpr size_t OFF_R3 = 11200000;   // h_perB
constexpr size_t OFF_R4 = 14400000;   // emp1B (6.4M) + per1B (@+6.4M, 3.2M)
constexpr size_t OFF_R5 = 27200000;   // p2epB (3.2M)
constexpr size_t OFF_R6 = 33600000;   // proj_eeB
constexpr size_t OFF_R7 = 40000000;   // proj_peB
constexpr size_t OFF_R8 = 43200000;   // proj_epB
constexpr size_t OFF_AS = 49600000;
constexpr size_t OFF_AD = 49700000;
constexpr size_t OFF_WB = 49800000;
constexpr size_t OFF_BS1= 49900000;
constexpr size_t OFF_BS2= 49900128;
constexpr size_t OFF_VV = 49900192;
constexpr size_t OFF_CNT    = 50000000;
constexpr size_t OFF_EE_OFF = 50250000;
constexpr size_t OFF_PE_OFF = 50350008;
constexpr size_t OFF_EP_OFF = 50450016;
constexpr size_t OFF_PART   = 50500024;
constexpr size_t OFF_EE_CSR = 50500416;
constexpr size_t OFF_PE_CSR = 52100416;
constexpr size_t OFF_EP_CSR = 52900416;

extern "C" void kernel_launch(void* const* d_in, const int* in_sizes, int n_in,
                              void* d_out, int out_size, void* d_ws, size_t ws_size,
                              hipStream_t stream)
{
    const float* x_emp = (const float*)d_in[0];
    const float* x_per = (const float*)d_in[1];
    const int* ee_src = (const int*)d_in[2];
    const int* ee_dst = (const int*)d_in[3];
    const int* pe_src = (const int*)d_in[4];
    const int* pe_dst = (const int*)d_in[5];
    const int* ep_src = (const int*)d_in[6];
    const int* ep_dst = (const int*)d_in[7];
    const float* lin_emp_w=(const float*)d_in[8],  *lin_emp_b=(const float*)d_in[9];
    const float* lin_per_w=(const float*)d_in[10], *lin_per_b=(const float*)d_in[11];
    const float* s1_ee_Wl=(const float*)d_in[12], *s1_ee_bl=(const float*)d_in[13], *s1_ee_Wr=(const float*)d_in[14];
    const float* s1_pe_Wl=(const float*)d_in[15], *s1_pe_bl=(const float*)d_in[16], *s1_pe_Wr=(const float*)d_in[17];
    const float* s1_ep_Wl=(const float*)d_in[18], *s1_ep_bl=(const float*)d_in[19], *s1_ep_Wr=(const float*)d_in[20];
    const float* gat_Wsrc=(const float*)d_in[21], *gat_Wdst=(const float*)d_in[22];
    const float* gat_asrc=(const float*)d_in[23], *gat_adst=(const float*)d_in[24], *gat_b=(const float*)d_in[25];
    const float* s2_pe_Wl=(const float*)d_in[26], *s2_pe_bl=(const float*)d_in[27], *s2_pe_Wr=(const float*)d_in[28];
    const float* s2_ep_Wl=(const float*)d_in[29], *s2_ep_bl=(const float*)d_in[30], *s2_ep_Wr=(const float*)d_in[31];

    float* ws = (float*)d_ws;
    int*   wi = (int*)d_ws;
    float* out_emp = (float*)d_out;
    float* out_per = out_emp + (size_t)NE_N*OUTD;

    uint16_t* xbe     = (uint16_t*)(ws + OFF_R0);
    uint16_t* zsB     = (uint16_t*)(ws + OFF_R0);
    uint16_t* xbp     = (uint16_t*)(ws + OFF_R1);
    uint16_t* p2peB   = (uint16_t*)(ws + OFF_R1);
    uint16_t* h_empB  = (uint16_t*)(ws + OFF_R2);
    uint16_t* h_perB  = (uint16_t*)(ws + OFF_R3);
    uint16_t* emp1B   = (uint16_t*)(ws + OFF_R4);
    uint16_t* per1B   = (uint16_t*)(ws + OFF_R4 + 6400000);
    uint16_t* p2epB   = (uint16_t*)(ws + OFF_R5);
    uint16_t* proj_eeB= (uint16_t*)(ws + OFF_R6);
    uint16_t* proj_peB= (uint16_t*)(ws + OFF_R7);
    uint16_t* proj_epB= (uint16_t*)(ws + OFF_R8);
    float* a_s   = ws + OFF_AS;
    float* a_d   = ws + OFF_AD;
    uint16_t* WB = (uint16_t*)(ws + OFF_WB);
    float* bsum1 = ws + OFF_BS1;
    float* b2sum = ws + OFF_BS2;
    float* vvec  = ws + OFF_VV;

    int* cnt_all = wi + OFF_CNT;
    int* ee_off = wi + OFF_EE_OFF; int* ee_csr = wi + OFF_EE_CSR;
    int* pe_off = wi + OFF_PE_OFF; int* pe_csr = wi + OFF_PE_CSR;
    int* ep_off = wi + OFF_EP_OFF; int* ep_csr = wi + OFF_EP_CSR;
    int* part   = wi + OFF_PART;

    const int GE = ceil_div(NE_N,256), GP = ceil_div(NPER_N,256);

    hipMemsetAsync(cnt_all, 0, 250000*sizeof(int), stream);

    prep<<<13,256,0,stream>>>(s1_ee_Wr, s1_pe_Wr, s1_ee_Wl, s1_ep_Wl, s1_pe_Wl, s1_ep_Wr,
                              lin_emp_w, lin_per_w,
                              gat_Wsrc, s2_ep_Wl, s2_pe_Wr, s2_pe_Wl, s2_ep_Wr,
                              s1_ee_bl, s1_pe_bl, s2_pe_bl, gat_b, gat_Wdst, gat_adst,
                              WB, bsum1, b2sum, vvec);
    convx<<<ceil_div(NE_N*64/4 + NPER_N*32/4, 256),256,0,stream>>>(x_emp, x_per, xbe, xbp);

    // ---- CSR build ----
    count_all<<<ceil_div(ETOT,256),256,0,stream>>>(ee_dst, pe_dst, ep_dst, cnt_all);
    scan_block3<<<dim3(ceil_div(NE_N,1024),3),256,0,stream>>>(cnt_all, ee_off, pe_off, ep_off, part);
    scan_partial3<<<3,64,0,stream>>>(part);
    add_base3<<<ceil_div(2*(NE_N+1)+NPER_N+1,256),256,0,stream>>>(ee_off, pe_off, ep_off, part);
    const int NCHUNK = ceil_div(ETOT,256);
    fill_sharded<<<NCHUNK*8,256,0,stream>>>(ee_src, ee_dst, pe_src, pe_dst, ep_src, ep_dst,
                                            ee_off, pe_off, ep_off, cnt_all,
                                            ee_csr, pe_csr, ep_csr);

    // ---- GEMMs ----
    {
        Segs g{};
        g.s[0] = Seg{WB+WB_LINE,    lin_emp_b,    (void*)h_empB,      nullptr,nullptr, 128,128,2};
        g.s[1] = Seg{WB+WB_LINE+64, lin_emp_b+64, (void*)(h_empB+64), nullptr,nullptr, 128,128,2};
        g.s[2]=g.s[0]; g.s[3]=g.s[0]; g.s[4]=g.s[0]; g.s[5]=g.s[0];
        gemm_mfma<64><<<dim3(GE,2),256,0,stream>>>(xbe, NE_N, g);
    }
    {
        Segs g{};
        g.s[0] = Seg{WB+WB_LINP,    lin_per_b,    (void*)h_perB,      nullptr,nullptr, 128,128,2};
        g.s[1] = Seg{WB+WB_LINP+64, lin_per_b+64, (void*)(h_perB+64), nullptr,nullptr, 128,128,2};
        g.s[2]=g.s[0]; g.s[3]=g.s[0]; g.s[4]=g.s[0]; g.s[5]=g.s[0];
        gemm_mfma<32><<<dim3(GP,2),256,0,stream>>>(xbp, NPER_N, g);
    }
    {   // conv1 from h_emp: emp1 base (bf16+bias), proj_ee, proj_ep
        Segs g{};
        g.s[0] = Seg{WB+WB_WSUM,    bsum1,    (void*)emp1B,        nullptr,nullptr, 128,128,3};
        g.s[1] = Seg{WB+WB_WSUM+64, bsum1+64, (void*)(emp1B+64),   nullptr,nullptr, 128,128,3};
        g.s[2] = Seg{WB+WB_EEWL,    nullptr,  (void*)proj_eeB,     nullptr,nullptr, 128,128,1};
        g.s[3] = Seg{WB+WB_EEWL+64, nullptr,  (void*)(proj_eeB+64),nullptr,nullptr, 128,128,1};
        g.s[4] = Seg{WB+WB_EPWL,    nullptr,  (void*)proj_epB,     nullptr,nullptr, 128,128,1};
        g.s[5] = Seg{WB+WB_EPWL+64, nullptr,  (void*)(proj_epB+64),nullptr,nullptr, 128,128,1};
        gemm_mfma<128><<<dim3(GE,6),256,0,stream>>>(h_empB, NE_N, g);
    }
    {   // conv1 from h_per: proj_pe, per1 base (bf16+bias)
        Segs g{};
        g.s[0] = Seg{WB+WB_PEWL,    nullptr,     (void*)proj_peB,     nullptr,nullptr, 128,128,1};
        g.s[1] = Seg{WB+WB_PEWL+64, nullptr,     (void*)(proj_peB+64),nullptr,nullptr, 128,128,1};
        g.s[2] = Seg{WB+WB_EPWR1,   s1_ep_bl,    (void*)per1B,        nullptr,nullptr, 128,128,3};
        g.s[3] = Seg{WB+WB_EPWR1+64,s1_ep_bl+64, (void*)(per1B+64),   nullptr,nullptr, 128,128,3};
        g.s[4]=g.s[0]; g.s[5]=g.s[0];
        gemm_mfma<128><<<dim3(GP,4),256,0,stream>>>(h_perB, NPER_N, g);
    }
    agg1_fused<<<ceil_div((long long)(NE_N+NPER_N)*64,256),256,0,stream>>>(
        proj_eeB, proj_peB, proj_epB, ee_off, ee_csr, pe_off, pe_csr, ep_off, ep_csr,
        emp1B, per1B, vvec, a_d);

    {   // conv2 from emp1: zs (+fused a_s), p2ep, emp2 base
        Segs g{};
        g.s[0] = Seg{WB+WB_GATW,   nullptr, (void*)zsB,     gat_asrc, a_s,  64,64,4};
        g.s[1] = Seg{WB+WB_S2EPWL, nullptr, (void*)p2epB,   nullptr, nullptr, 64,64,1};
        g.s[2] = Seg{WB+WB_S2PEWR, b2sum,   (void*)out_emp, nullptr, nullptr, 64,64,0};
        g.s[3]=g.s[1]; g.s[4]=g.s[1]; g.s[5]=g.s[1];
        gemm_mfma<128><<<dim3(GE,3),256,0,stream>>>(emp1B, NE_N, g);
    }
    {   // conv2 from per1
        Segs g{};
        g.s[0] = Seg{WB+WB_S2PEWL, nullptr,  (void*)p2peB,   nullptr,nullptr, 64,64,1};
        g.s[1] = Seg{WB+WB_S2EPWR, s2_ep_bl, (void*)out_per, nullptr,nullptr, 64,64,0};
        g.s[2]=g.s[0]; g.s[3]=g.s[0]; g.s[4]=g.s[0]; g.s[5]=g.s[0];
        gemm_mfma<128><<<dim3(GP,2),256,0,stream>>>(per1B, NPER_N, g);
    }

    agg2_fused<<<ceil_div((long long)(NE_N+NPER_N)*64,256),256,0,stream>>>(
        ee_off, ee_csr, pe_off, pe_csr, ep_off, ep_csr, a_s, a_d,
        zsB, p2peB, p2epB, out_emp, out_per);
}